// Round 11
// baseline (378.827 us; speedup 1.0000x reference)
//
#include <hip/hip_runtime.h>

#define AS1 __attribute__((address_space(1)))
#define AS3 __attribute__((address_space(3)))

typedef __bf16 bf16;
typedef __bf16 bf16x8 __attribute__((ext_vector_type(8)));
typedef float f32x4 __attribute__((ext_vector_type(4)));

__device__ __forceinline__ void gld_lds16(const bf16* g, bf16* l) {
    __builtin_amdgcn_global_load_lds((const AS1 void*)g, (AS3 void*)l, 16, 0, 0);
}

#define SB0 __builtin_amdgcn_sched_barrier(0)
#define BARX do { SB0; __builtin_amdgcn_s_barrier(); SB0; } while (0)

// ---------------- fused fp32 -> bf16 cast (all 5 tensors, one launch) ----------------
__global__ void cvt_all_kernel(const float4* __restrict__ h, const float4* __restrict__ wq,
                               const float4* __restrict__ wk, const float4* __restrict__ wv,
                               const float4* __restrict__ wo, ushort4* __restrict__ hs,
                               ushort4* __restrict__ wb) {
    const int i = blockIdx.x * 256 + threadIdx.x;   // 0 .. 12582911
    const float4* src;
    ushort4* dst;
    if (i < 2097152)      { src = h  + i;             dst = hs + i; }
    else if (i < 6291456) { src = wq + (i - 2097152); dst = wb + (i - 2097152); }
    else if (i < 7340032) { src = wk + (i - 6291456); dst = wb + 4194304 + (i - 6291456); }
    else if (i < 8388608) { src = wv + (i - 7340032); dst = wb + 5242880 + (i - 7340032); }
    else                  { src = wo + (i - 8388608); dst = wb + 6291456 + (i - 8388608); }
    const float4 v = *src;
    ushort4 r;
    r.x = __builtin_bit_cast(unsigned short, (bf16)v.x);
    r.y = __builtin_bit_cast(unsigned short, (bf16)v.y);
    r.z = __builtin_bit_cast(unsigned short, (bf16)v.z);
    r.w = __builtin_bit_cast(unsigned short, (bf16)v.w);
    *dst = r;
}

// ---------------- 8-phase 256x256 GEMM, counted vmcnt, swizzled LDS (R9, frozen) ----------------
template <bool OUTF32>
__launch_bounds__(512, 2)
__global__ void gemm_8ph_kernel(const bf16* __restrict__ A, const bf16* __restrict__ W,
                                void* __restrict__ Cout, int M, int N, int K) {
    __shared__ __align__(16) bf16 Asl[2][256 * 64];
    __shared__ __align__(16) bf16 Bsl[2][256 * 64];

    const int tn = blockIdx.x * 256;
    const int tm = blockIdx.y * 256;
    const int tid = threadIdx.x;
    const int wave = tid >> 6;
    const int lane = tid & 63;
    const int laneR = lane & 15;
    const int laneS = lane >> 4;
    const int wmB = (wave >> 2) * 128;
    const int wnB = (wave & 3) * 64;
    const int NT = K >> 6;
    const int NI = NT >> 1;

    auto stageA = [&](int t, int h) {
        if (t >= NT) return;
        const int d = t & 1, k0 = t << 6;
#pragma unroll
        for (int iss = 0; iss < 2; ++iss) {
            const int c = iss * 512 + tid;
            const int row = c >> 3, sl = c & 7;
            gld_lds16(A + (size_t)(tm + h * 128 + row) * K + k0 + ((sl ^ (row & 7)) << 3),
                      &Asl[d][h * 8192 + (iss * 512 + wave * 64) * 8]);
        }
    };
    auto stageB = [&](int t, int h) {
        if (t >= NT) return;
        const int d = t & 1, k0 = t << 6;
#pragma unroll
        for (int iss = 0; iss < 2; ++iss) {
            const int c = iss * 512 + tid;
            const int row = c >> 3, sl = c & 7;
            gld_lds16(W + (size_t)(tn + h * 128 + row) * K + k0 + ((sl ^ (row & 7)) << 3),
                      &Bsl[d][h * 8192 + (iss * 512 + wave * 64) * 8]);
        }
    };

    bf16x8 aF[8], bF0[4], bF1[4];
    f32x4 acc[8][4] = {};

#define RD_A(d, mh) do { _Pragma("unroll") for (int m = 0; m < 4; ++m) \
    _Pragma("unroll") for (int ks = 0; ks < 2; ++ks) { \
        const int row_ = wmB + (mh) * 64 + m * 16 + laneR; \
        const int sl_ = (ks * 4 + laneS) ^ (row_ & 7); \
        aF[m * 2 + ks] = *(const bf16x8*)&Asl[d][row_ * 64 + sl_ * 8]; } } while (0)

#define RD_B(d, nh, DST) do { _Pragma("unroll") for (int n = 0; n < 2; ++n) \
    _Pragma("unroll") for (int ks = 0; ks < 2; ++ks) { \
        const int row_ = wnB + (nh) * 32 + n * 16 + laneR; \
        const int sl_ = (ks * 4 + laneS) ^ (row_ & 7); \
        DST[n * 2 + ks] = *(const bf16x8*)&Bsl[d][row_ * 64 + sl_ * 8]; } } while (0)

#define MMAQ(mh, nh, BSRC) do { __builtin_amdgcn_s_setprio(1); \
    _Pragma("unroll") for (int m = 0; m < 4; ++m) \
    _Pragma("unroll") for (int n = 0; n < 2; ++n) \
    _Pragma("unroll") for (int ks = 0; ks < 2; ++ks) \
        acc[(mh) * 4 + m][(nh) * 2 + n] = __builtin_amdgcn_mfma_f32_16x16x32_bf16( \
            aF[m * 2 + ks], BSRC[n * 2 + ks], acc[(mh) * 4 + m][(nh) * 2 + n], 0, 0, 0); \
    __builtin_amdgcn_s_setprio(0); } while (0)

    stageA(0, 0); stageA(0, 1); stageB(0, 0); stageB(0, 1); stageA(1, 0);
    SB0; asm volatile("s_waitcnt vmcnt(2)" ::: "memory"); BARX;

    for (int i = 0; i < NI; ++i) {
        const int u = i * 2;
        const bool last = (i == NI - 1);
        RD_A(0, 0); RD_B(0, 0, bF0); stageA(u + 1, 1);
        BARX; MMAQ(0, 0, bF0); BARX;
        RD_B(0, 1, bF1); stageB(u + 1, 0);
        BARX; MMAQ(0, 1, bF1); BARX;
        RD_A(0, 1); stageB(u + 1, 1);
        BARX; MMAQ(1, 1, bF1); BARX;
        RD_B(0, 0, bF0); stageA(u + 2, 0);
        BARX; MMAQ(1, 0, bF0);
        SB0;
        if (last) asm volatile("s_waitcnt vmcnt(0)" ::: "memory");
        else      asm volatile("s_waitcnt vmcnt(2)" ::: "memory");
        BARX;
        RD_A(1, 0); RD_B(1, 0, bF0); stageA(u + 2, 1);
        BARX; MMAQ(0, 0, bF0); BARX;
        RD_B(1, 1, bF1); stageB(u + 2, 0);
        BARX; MMAQ(0, 1, bF1); BARX;
        RD_A(1, 1); stageB(u + 2, 1);
        BARX; MMAQ(1, 1, bF1); BARX;
        RD_B(1, 0, bF0); stageA(u + 3, 0);
        BARX; MMAQ(1, 0, bF0);
        SB0;
        if (last) asm volatile("s_waitcnt vmcnt(0)" ::: "memory");
        else      asm volatile("s_waitcnt vmcnt(2)" ::: "memory");
        BARX;
    }
#undef RD_A
#undef RD_B
#undef MMAQ

    const int rbase = laneS * 4;
#pragma unroll
    for (int mf = 0; mf < 8; ++mf)
#pragma unroll
        for (int nf = 0; nf < 4; ++nf)
#pragma unroll
            for (int rr = 0; rr < 4; ++rr) {
                const size_t row = (size_t)tm + wmB + mf * 16 + rbase + rr;
                const size_t col = (size_t)tn + wnB + nf * 16 + laneR;
                if constexpr (OUTF32) ((float*)Cout)[row * N + col] = acc[mf][nf][rr];
                else                  ((bf16*)Cout)[row * N + col] = (bf16)acc[mf][nf][rr];
            }
    (void)M;
}

// ---------------- GEMM, R7 counted-vmcnt 4-slot ring + conflict-free swizzle (R10, frozen) ----------------
template <int BN, bool OUTF32>
__launch_bounds__(512, 2)
__global__ void gemm8p_kernel(const bf16* __restrict__ A, const bf16* __restrict__ W,
                              void* __restrict__ Cout, int M, int N, int K) {
    constexpr int NF = BN / 64;
    constexpr int IB = BN / 128;
    __shared__ __align__(16) bf16 Asl[4][128 * 32];
    __shared__ __align__(16) bf16 Bsl[4][BN * 32];

    const int tn = blockIdx.x * BN;
    const int tm = blockIdx.y * 128;
    const int tid = threadIdx.x;
    const int wave = tid >> 6;
    const int lane = tid & 63;
    const int laneR = lane & 15;
    const int laneS = lane >> 4;
    const int wmB = (wave >> 2) * 64;
    const int wnB = (wave & 3) * (BN / 4);
    const int NT = K >> 5;
    const int sofs = (laneS ^ ((laneR >> 1) & 3)) << 3;

    auto stage = [&](int t) {
        const int slot = t & 3;
        const int k0 = t << 5;
        {
            const int row = tid >> 2, g = tid & 3;
            const int sg = g ^ ((row >> 1) & 3);
            gld_lds16(A + (size_t)(tm + row) * K + k0 + sg * 8, &Asl[slot][wave * 512]);
        }
#pragma unroll
        for (int i = 0; i < IB; ++i) {
            const int row = i * 128 + (tid >> 2), g = tid & 3;
            const int sg = g ^ ((row >> 1) & 3);
            gld_lds16(W + (size_t)(tn + row) * K + k0 + sg * 8,
                      &Bsl[slot][i * 4096 + wave * 512]);
        }
    };

    f32x4 acc[4][NF] = {};

    stage(0); stage(1); stage(2);
    asm volatile("s_waitcnt vmcnt(6)" ::: "memory");
    SB0;
    __builtin_amdgcn_s_barrier();
    SB0;

    for (int t = 0; t < NT; ++t) {
        const int slot = t & 3;
        bf16x8 af[4], bfr[NF];
#pragma unroll
        for (int mf = 0; mf < 4; ++mf)
            af[mf] = *(const bf16x8*)&Asl[slot][(wmB + mf * 16 + laneR) * 32 + sofs];
#pragma unroll
        for (int nf = 0; nf < NF; ++nf)
            bfr[nf] = *(const bf16x8*)&Bsl[slot][(wnB + nf * 16 + laneR) * 32 + sofs];

        if (t + 3 < NT) stage(t + 3);

#pragma unroll
        for (int mf = 0; mf < 4; ++mf)
#pragma unroll
            for (int nf = 0; nf < NF; ++nf)
                acc[mf][nf] = __builtin_amdgcn_mfma_f32_16x16x32_bf16(af[mf], bfr[nf], acc[mf][nf], 0, 0, 0);

        SB0;
        if (t + 3 < NT)       asm volatile("s_waitcnt vmcnt(6)" ::: "memory");
        else if (t + 3 == NT) asm volatile("s_waitcnt vmcnt(3)" ::: "memory");
        else                  asm volatile("s_waitcnt vmcnt(0)" ::: "memory");
        SB0;
        __builtin_amdgcn_s_barrier();
        SB0;
    }

    const int rbase = laneS * 4;
#pragma unroll
    for (int mf = 0; mf < 4; ++mf)
#pragma unroll
        for (int nf = 0; nf < NF; ++nf)
#pragma unroll
            for (int rr = 0; rr < 4; ++rr) {
                const size_t row = (size_t)tm + wmB + mf * 16 + rbase + rr;
                const size_t col = (size_t)tn + wnB + nf * 16 + laneR;
                if constexpr (OUTF32) ((float*)Cout)[row * N + col] = acc[mf][nf][rr];
                else                  ((bf16*)Cout)[row * N + col] = (bf16)acc[mf][nf][rr];
            }
    (void)M;
}

// ---------------- RoPE cos/sin table gen ----------------
__global__ void rope_table_kernel(float* __restrict__ ct, float* __restrict__ st) {
    const int idx = blockIdx.x * 256 + threadIdx.x;
    const int f = idx & 63;
    const int s = idx >> 6;
    const float th = s * expf(-0.14391156831212787f * (float)f);
    ct[idx] = cosf(th);
    st[idx] = sinf(th);
}

// ---------------- RoPE on q (pre-scaled by log2e/sqrt(D)) and k; table-based ----------------
__global__ void rope_qk_kernel(const bf16* __restrict__ C, bf16* __restrict__ Qr, bf16* __restrict__ Kr,
                               const float* __restrict__ ct, const float* __restrict__ st) {
    const int idx = blockIdx.x * 256 + threadIdx.x;
    const int NQ = 2048 * 32 * 64;
    const float QSC = 0.12751743561884394f;        // (1/sqrt(128)) * log2(e)
    if (idx < NQ) {
        const int f = idx & 63;
        const int t = idx >> 6;
        const int h = t & 31;
        const int s = t >> 5;
        const float x1 = (float)C[(size_t)s * 6144 + h * 128 + f];
        const float x2 = (float)C[(size_t)s * 6144 + h * 128 + f + 64];
        const float cs = ct[(s << 6) + f], sn = st[(s << 6) + f];
        bf16* dst = Qr + ((size_t)h * 2048 + s) * 128 + f;
        dst[0]  = (bf16)((x1 * cs - x2 * sn) * QSC);
        dst[64] = (bf16)((x2 * cs + x1 * sn) * QSC);
    } else {
        const int i2 = idx - NQ;
        const int f = i2 & 63;
        const int t = i2 >> 6;
        const int h = t & 7;
        const int s = t >> 3;
        const float x1 = (float)C[(size_t)s * 6144 + 4096 + h * 128 + f];
        const float x2 = (float)C[(size_t)s * 6144 + 4096 + h * 128 + f + 64];
        const float cs = ct[(s << 6) + f], sn = st[(s << 6) + f];
        bf16* dst = Kr + ((size_t)h * 2048 + s) * 128 + f;
        dst[0]  = (bf16)(x1 * cs - x2 * sn);
        dst[64] = (bf16)(x2 * cs + x1 * sn);
    }
}

// ---------------- V transpose: C_qkv v-cols -> Vt[hkv][d=128][s=2048] ----------------
__global__ void transpose_v_kernel(const bf16* __restrict__ C, bf16* __restrict__ Vt) {
    __shared__ __align__(16) unsigned short t[64][136];
    const int hkv = blockIdx.x >> 5;
    const int st = blockIdx.x & 31;
    const int s0 = st * 64;
    const int tid = threadIdx.x;
#pragma unroll
    for (int it = 0; it < 4; ++it) {
        const int l = it * 2048 + tid * 8;
        const int r = l >> 7, c = l & 127;
        *(bf16x8*)&t[r][c] = *(const bf16x8*)&C[(size_t)(s0 + r) * 6144 + 5120 + hkv * 128 + c];
    }
    __syncthreads();
#pragma unroll
    for (int it = 0; it < 8; ++it) {
        const int o = it * 1024 + tid * 4;
        const int d = o >> 6, j = o & 63;
        ushort4 pk;
        pk.x = t[j + 0][d];
        pk.y = t[j + 1][d];
        pk.z = t[j + 2][d];
        pk.w = t[j + 3][d];
        *(ushort4*)&Vt[((size_t)hkv * 128 + d) * 2048 + s0 + j] = pk;
    }
}

// ---------------- causal GQA flash attention v2: 2 blocks/CU, 64KB LDS ----------------
// Grid 512 = 32 heads x 16 q-blocks (128 rows each), heavy-first (qb = 15 - bid>>5),
// hkv = bid&7 for XCD L2 affinity. Block = 4 waves x 32 q-rows. KVBLK=64.
// LDS 64KB: K dbuf 2x16KB + V dbuf 2x16KB; P (4KB/wave) ALIASES the active K buffer
// after a mid-tile raw s_barrier (all waves' QK reads done; no vmcnt drain so the
// tile-top prefetch stays in flight). End-of-tile: vmcnt(0) (hidden by a full tile
// of compute) + s_barrier. Race-proof: K[buf] (holding P) is only re-staged by tile
// t+1's top (after tile t's end barrier, PV reads done); nbuf regions' last readers
// finished before the previous end barrier. Swizzles/mask/softmax = R5-verified.
__launch_bounds__(256, 2)
__global__ void flash_attn_kernel(const bf16* __restrict__ Qr, const bf16* __restrict__ Kr,
                                  const bf16* __restrict__ Vt, bf16* __restrict__ Aout) {
    __shared__ __align__(16) bf16 Klds[2][64 * 128];    // [kv][d], swizzled, 2x16KB
    __shared__ __align__(16) bf16 Vlds[2][128 * 64];    // [d][kv], swizzled, 2x16KB

    const int bid = blockIdx.x;
    const int hkv = bid & 7;
    const int hh = (bid >> 3) & 3;
    const int qb = 15 - (bid >> 5);          // heavy blocks dispatched first
    const int h = hkv * 4 + hh;
    const int tid = threadIdx.x;
    const int wave = tid >> 6, lane = tid & 63;
    const int laneR = lane & 15;
    const int laneS = lane >> 4;
    const int laneK = laneS * 8;
    const int rbase = laneS * 4;
    const int q0w = qb * 128 + wave * 32;

    const bf16* Kh = Kr + (size_t)hkv * 2048 * 128;
    const bf16* Vh = Vt + (size_t)hkv * 128 * 2048;

    auto stageK = [&](int kv0, int buf) {
#pragma unroll
        for (int s = 0; s < 4; ++s) {
            const int chunk = wave * 4 + s;
            const int L = chunk * 64 + lane;        // 16B-slot index
            const int krow = L >> 4, kc16 = L & 15; // 16 slots per 256B row
            gld_lds16(Kh + (size_t)(kv0 + krow) * 128 + ((kc16 ^ (krow & 7)) << 3),
                      &Klds[buf][chunk * 512]);
        }
    };
    auto stageV = [&](int kv0, int buf) {
#pragma unroll
        for (int s = 0; s < 4; ++s) {
            const int chunk = wave * 4 + s;
            const int L = chunk * 64 + lane;
            const int vrow = L >> 3, vc8 = L & 7;   // 8 slots per 128B row
            gld_lds16(Vh + (size_t)vrow * 2048 + kv0 + ((vc8 ^ (vrow & 7)) << 3),
                      &Vlds[buf][chunk * 512]);
        }
    };

    // Q fragments (pre-scaled by log2e/sqrt(D))
    bf16x8 qf[2][4];
#pragma unroll
    for (int mi = 0; mi < 2; ++mi)
#pragma unroll
        for (int kc = 0; kc < 4; ++kc)
            qf[mi][kc] = *(const bf16x8*)&Qr[((size_t)h * 2048 + q0w + mi * 16 + laneR) * 128 + kc * 32 + laneK];

    f32x4 o[2][8] = {};
    float mrow[2][4], lrow[2][4];
#pragma unroll
    for (int mi = 0; mi < 2; ++mi)
#pragma unroll
        for (int rr = 0; rr < 4; ++rr) { mrow[mi][rr] = -1e30f; lrow[mi][rr] = 0.f; }

    const int ntiles = 2 * qb + 2;
    stageK(0, 0);
    stageV(0, 0);
    SB0; asm volatile("s_waitcnt vmcnt(0)" ::: "memory"); BARX;

    for (int t = 0; t < ntiles; ++t) {
        const int buf = t & 1;
        const int kv0 = t * 64;
        if (t + 1 < ntiles) {                 // prefetch stays in flight across barrier #1
            stageK(kv0 + 64, buf ^ 1);
            stageV(kv0 + 64, buf ^ 1);
        }
        const bool live = (kv0 <= q0w + 31);

        f32x4 sc[2][4] = {};
        if (live) {
            __builtin_amdgcn_s_setprio(1);
#pragma unroll
            for (int kc = 0; kc < 4; ++kc) {
                bf16x8 kf[4];
#pragma unroll
                for (int j = 0; j < 4; ++j) {
                    const int row = j * 16 + laneR;
                    kf[j] = *(const bf16x8*)((const char*)Klds[buf] + row * 256 +
                                             ((kc * 64 + laneS * 16) ^ ((row & 7) << 4)));
                }
#pragma unroll
                for (int mi = 0; mi < 2; ++mi)
#pragma unroll
                    for (int j = 0; j < 4; ++j)
                        sc[mi][j] = __builtin_amdgcn_mfma_f32_16x16x32_bf16(qf[mi][kc], kf[j], sc[mi][j], 0, 0, 0);
            }
            __builtin_amdgcn_s_setprio(0);
        }

        BARX;   // #1: all waves' QK reads of Klds[buf] consumed -> P may alias into it

        if (live) {
            if (kv0 + 63 > q0w) {   // diagonal region: causal mask
#pragma unroll
                for (int mi = 0; mi < 2; ++mi)
#pragma unroll
                    for (int j = 0; j < 4; ++j)
#pragma unroll
                        for (int rr = 0; rr < 4; ++rr) {
                            const int qr = q0w + mi * 16 + rbase + rr;
                            const int kr = kv0 + j * 16 + laneR;
                            if (kr > qr) sc[mi][j][rr] = -1e30f;
                        }
            }

            // online softmax, defer-max (THR=8)
#pragma unroll
            for (int mi = 0; mi < 2; ++mi) {
#pragma unroll
                for (int rr = 0; rr < 4; ++rr) {
                    float v = sc[mi][0][rr];
#pragma unroll
                    for (int j = 1; j < 4; ++j) v = fmaxf(v, sc[mi][j][rr]);
                    v = fmaxf(v, __shfl_xor(v, 1, 64));
                    v = fmaxf(v, __shfl_xor(v, 2, 64));
                    v = fmaxf(v, __shfl_xor(v, 4, 64));
                    v = fmaxf(v, __shfl_xor(v, 8, 64));
                    float m0 = mrow[mi][rr];
                    if (v - m0 > 8.0f) {
                        const float fac = __builtin_exp2f(m0 - v);
                        mrow[mi][rr] = v;
                        m0 = v;
                        lrow[mi][rr] *= fac;
#pragma unroll
                        for (int j = 0; j < 8; ++j) o[mi][j][rr] *= fac;
                    }
                    float rs = 0.f;
#pragma unroll
                    for (int j = 0; j < 4; ++j) {
                        const float p = __builtin_exp2f(sc[mi][j][rr] - m0);
                        sc[mi][j][rr] = p;
                        rs += p;
                    }
                    rs += __shfl_xor(rs, 1, 64);
                    rs += __shfl_xor(rs, 2, 64);
                    rs += __shfl_xor(rs, 4, 64);
                    rs += __shfl_xor(rs, 8, 64);
                    lrow[mi][rr] += rs;
                }
            }

            // P -> per-wave quarter of the ACTIVE K buffer (safe after barrier #1)
            char* Pw = (char*)Klds[buf] + wave * 4096;
#pragma unroll
            for (int mi = 0; mi < 2; ++mi)
#pragma unroll
                for (int j = 0; j < 4; ++j)
#pragma unroll
                    for (int rr = 0; rr < 4; ++rr) {
                        const int row = mi * 16 + rbase + rr;
                        *(bf16*)(Pw + row * 128 + ((j * 32 + laneR * 2) ^ ((row & 7) << 4))) =
                            (bf16)sc[mi][j][rr];
                    }

            // O += P V
            __builtin_amdgcn_s_setprio(1);
#pragma unroll
            for (int kc = 0; kc < 2; ++kc) {
                bf16x8 pf[2];
#pragma unroll
                for (int mi = 0; mi < 2; ++mi) {
                    const int row = mi * 16 + laneR;
                    pf[mi] = *(const bf16x8*)(Pw + row * 128 + ((kc * 64 + laneS * 16) ^ ((row & 7) << 4)));
                }
                bf16x8 vf[8];
#pragma unroll
                for (int j = 0; j < 8; ++j) {
                    const int row = j * 16 + laneR;
                    vf[j] = *(const bf16x8*)((const char*)Vlds[buf] + row * 128 +
                                             ((kc * 64 + laneS * 16) ^ ((row & 7) << 4)));
                }
#pragma unroll
                for (int mi = 0; mi < 2; ++mi)
#pragma unroll
                    for (int j = 0; j < 8; ++j)
                        o[mi][j] = __builtin_amdgcn_mfma_f32_16x16x32_bf16(pf[mi], vf[j], o[mi][j], 0, 0, 0);
            }
            __builtin_amdgcn_s_setprio(0);
        }

        // #2: prefetch landed (vmcnt0, issued a full tile ago) + all waves done with buf
        SB0; asm volatile("s_waitcnt vmcnt(0)" ::: "memory"); BARX;
    }

    // normalize + write attn output [s][h*128+d]
#pragma unroll
    for (int mi = 0; mi < 2; ++mi) {
        float rinv[4];
#pragma unroll
        for (int rr = 0; rr < 4; ++rr) rinv[rr] = 1.0f / lrow[mi][rr];
#pragma unroll
        for (int j = 0; j < 8; ++j)
#pragma unroll
            for (int rr = 0; rr < 4; ++rr) {
                const size_t row = (size_t)q0w + mi * 16 + rbase + rr;
                Aout[row * 4096 + h * 128 + j * 16 + laneR] = (bf16)(o[mi][j][rr] * rinv[rr]);
            }
    }
}

// ---------------- launch ----------------
extern "C" void kernel_launch(void* const* d_in, const int* in_sizes, int n_in,
                              void* d_out, int out_size, void* d_ws, size_t ws_size,
                              hipStream_t stream) {
    const float* hidden = (const float*)d_in[0];
    const float* Wq = (const float*)d_in[1];
    const float* Wk = (const float*)d_in[2];
    const float* Wv = (const float*)d_in[3];
    const float* Wo = (const float*)d_in[4];
    float* out = (float*)d_out;
    char* ws = (char*)d_ws;

    // workspace layout (bytes):
    bf16* hs = (bf16*)(ws + 0);                 // [2048][4096]        16 MiB (dead after QKV)
    bf16* Wb = (bf16*)(ws + 16777216);          // [10240][4096]       80 MiB (Wq|Wk|Wv|Wo)
    bf16* Cq = (bf16*)(ws + 100663296);         // [2048][6144]        24 MiB
    bf16* Qr = (bf16*)(ws + 125829120);         // [32][2048][128]     16 MiB
    bf16* Kr = (bf16*)(ws + 142606336);         // [8][2048][128]       4 MiB
    bf16* Vt = (bf16*)(ws + 146800640);         // [8][128][2048]       4 MiB
    bf16* At = (bf16*)(ws + 150994944);         // [2048][4096]        16 MiB
    float* ct = (float*)(ws + 0);               // rope cos table (aliases dead hs)
    float* st = (float*)(ws + 524288);          // rope sin table
    (void)ws_size; (void)in_sizes; (void)n_in; (void)out_size;

    // 1. fused casts
    cvt_all_kernel<<<49152, 256, 0, stream>>>((const float4*)hidden, (const float4*)Wq,
                                              (const float4*)Wk, (const float4*)Wv,
                                              (const float4*)Wo, (ushort4*)hs, (ushort4*)Wb);

    // 2. fused QKV projection (256x256 8-phase -> 192 blocks)
    gemm_8ph_kernel<false><<<dim3(24, 8), 512, 0, stream>>>(hs, Wb, Cq, 2048, 6144, 4096);

    // 3. rope tables + RoPE
    rope_table_kernel<<<512, 256, 0, stream>>>(ct, st);
    rope_qk_kernel<<<20480, 256, 0, stream>>>(Cq, Qr, Kr, ct, st);

    // 4. V transpose -> [hkv][d][s]
    transpose_v_kernel<<<256, 256, 0, stream>>>(Cq, Vt);

    // 5. causal GQA flash attention v2 (512 blocks, 2/CU)
    flash_attn_kernel<<<512, 256, 0, stream>>>(Qr, Kr, Vt, At);

    // 6. output projection (R7 ring + swizzle, 128x256 -> 256 blocks)
    gemm8p_kernel<256, true><<<dim3(16, 16), 512, 0, stream>>>(At, Wb + 25165824, out, 2048, 4096, 4096);
}

// Round 12
// 339.318 us; speedup vs baseline: 1.1164x; 1.1164x over previous
//
#include <hip/hip_runtime.h>

#define AS1 __attribute__((address_space(1)))
#define AS3 __attribute__((address_space(3)))

typedef __bf16 bf16;
typedef __bf16 bf16x8 __attribute__((ext_vector_type(8)));
typedef float f32x4 __attribute__((ext_vector_type(4)));

__device__ __forceinline__ void gld_lds16(const bf16* g, bf16* l) {
    __builtin_amdgcn_global_load_lds((const AS1 void*)g, (AS3 void*)l, 16, 0, 0);
}

#define SB0 __builtin_amdgcn_sched_barrier(0)

// ---------------- fused fp32 -> bf16 cast (all 5 tensors, one launch) ----------------
__global__ void cvt_all_kernel(const float4* __restrict__ h, const float4* __restrict__ wq,
                               const float4* __restrict__ wk, const float4* __restrict__ wv,
                               const float4* __restrict__ wo, ushort4* __restrict__ hs,
                               ushort4* __restrict__ wb) {
    const int i = blockIdx.x * 256 + threadIdx.x;   // 0 .. 12582911
    const float4* src;
    ushort4* dst;
    if (i < 2097152)      { src = h  + i;             dst = hs + i; }
    else if (i < 6291456) { src = wq + (i - 2097152); dst = wb + (i - 2097152); }
    else if (i < 7340032) { src = wk + (i - 6291456); dst = wb + 4194304 + (i - 6291456); }
    else if (i < 8388608) { src = wv + (i - 7340032); dst = wb + 5242880 + (i - 7340032); }
    else                  { src = wo + (i - 8388608); dst = wb + 6291456 + (i - 8388608); }
    const float4 v = *src;
    ushort4 r;
    r.x = __builtin_bit_cast(unsigned short, (bf16)v.x);
    r.y = __builtin_bit_cast(unsigned short, (bf16)v.y);
    r.z = __builtin_bit_cast(unsigned short, (bf16)v.z);
    r.w = __builtin_bit_cast(unsigned short, (bf16)v.w);
    *dst = r;
}

// ---------------- GEMM: counted-vmcnt 4-slot ring + conflict-free slot-XOR swizzle ----------------
// C[M,N] = A[M,K] * W[N,K]^T, row-major K-contiguous, mfma 16x16x32 bf16.
// Tile 128 x BN, BK=32, 512 threads (8 waves, 2M x 4N). Ring of 4 K-slots; tile t
// computes slot t&3 while t+3 stages into (t-1)&3 (readers done at t-1's barrier).
// Counted s_waitcnt vmcnt(2I) per tile (I = stage issues/thread; 0 only in tail).
// Swizzle (R8/R10-validated, 0 conflicts): 64B rows = 4 x 16B slots,
// slot' = slot ^ ((row>>1)&3); linear gld_lds dest + inverse-permuted global source;
// reads apply the same XOR.
template <int BN, bool OUTF32>
__launch_bounds__(512, 2)
__global__ void gemm8p_kernel(const bf16* __restrict__ A, const bf16* __restrict__ W,
                              void* __restrict__ Cout, int M, int N, int K) {
    constexpr int NF = BN / 64;
    constexpr int IB = BN / 128;
    __shared__ __align__(16) bf16 Asl[4][128 * 32];
    __shared__ __align__(16) bf16 Bsl[4][BN * 32];

    const int tn = blockIdx.x * BN;
    const int tm = blockIdx.y * 128;
    const int tid = threadIdx.x;
    const int wave = tid >> 6;
    const int lane = tid & 63;
    const int laneR = lane & 15;
    const int laneS = lane >> 4;
    const int wmB = (wave >> 2) * 64;
    const int wnB = (wave & 3) * (BN / 4);
    const int NT = K >> 5;
    const int sofs = (laneS ^ ((laneR >> 1) & 3)) << 3;

    auto stage = [&](int t) {
        const int slot = t & 3;
        const int k0 = t << 5;
        {
            const int row = tid >> 2, g = tid & 3;
            const int sg = g ^ ((row >> 1) & 3);
            gld_lds16(A + (size_t)(tm + row) * K + k0 + sg * 8, &Asl[slot][wave * 512]);
        }
#pragma unroll
        for (int i = 0; i < IB; ++i) {
            const int row = i * 128 + (tid >> 2), g = tid & 3;
            const int sg = g ^ ((row >> 1) & 3);
            gld_lds16(W + (size_t)(tn + row) * K + k0 + sg * 8,
                      &Bsl[slot][i * 4096 + wave * 512]);
        }
    };

    f32x4 acc[4][NF] = {};

    stage(0); stage(1); stage(2);
    if constexpr (BN == 384) asm volatile("s_waitcnt vmcnt(8)" ::: "memory");
    else                     asm volatile("s_waitcnt vmcnt(6)" ::: "memory");
    SB0;
    __builtin_amdgcn_s_barrier();
    SB0;

    for (int t = 0; t < NT; ++t) {
        const int slot = t & 3;
        bf16x8 af[4], bfr[NF];
#pragma unroll
        for (int mf = 0; mf < 4; ++mf)
            af[mf] = *(const bf16x8*)&Asl[slot][(wmB + mf * 16 + laneR) * 32 + sofs];
#pragma unroll
        for (int nf = 0; nf < NF; ++nf)
            bfr[nf] = *(const bf16x8*)&Bsl[slot][(wnB + nf * 16 + laneR) * 32 + sofs];

        if (t + 3 < NT) stage(t + 3);

#pragma unroll
        for (int mf = 0; mf < 4; ++mf)
#pragma unroll
            for (int nf = 0; nf < NF; ++nf)
                acc[mf][nf] = __builtin_amdgcn_mfma_f32_16x16x32_bf16(af[mf], bfr[nf], acc[mf][nf], 0, 0, 0);

        SB0;
        if (t + 3 < NT) {
            if constexpr (BN == 384) asm volatile("s_waitcnt vmcnt(8)" ::: "memory");
            else                     asm volatile("s_waitcnt vmcnt(6)" ::: "memory");
        } else if (t + 3 == NT) {
            if constexpr (BN == 384) asm volatile("s_waitcnt vmcnt(4)" ::: "memory");
            else                     asm volatile("s_waitcnt vmcnt(3)" ::: "memory");
        } else {
            asm volatile("s_waitcnt vmcnt(0)" ::: "memory");
        }
        SB0;
        __builtin_amdgcn_s_barrier();
        SB0;
    }

    const int rbase = laneS * 4;
#pragma unroll
    for (int mf = 0; mf < 4; ++mf)
#pragma unroll
        for (int nf = 0; nf < NF; ++nf)
#pragma unroll
            for (int rr = 0; rr < 4; ++rr) {
                const size_t row = (size_t)tm + wmB + mf * 16 + rbase + rr;
                const size_t col = (size_t)tn + wnB + nf * 16 + laneR;
                if constexpr (OUTF32) ((float*)Cout)[row * N + col] = acc[mf][nf][rr];
                else                  ((bf16*)Cout)[row * N + col] = (bf16)acc[mf][nf][rr];
            }
    (void)M;
}

// ---------------- RoPE cos/sin table gen ----------------
__global__ void rope_table_kernel(float* __restrict__ ct, float* __restrict__ st) {
    const int idx = blockIdx.x * 256 + threadIdx.x;
    const int f = idx & 63;
    const int s = idx >> 6;
    const float th = s * expf(-0.14391156831212787f * (float)f);
    ct[idx] = cosf(th);
    st[idx] = sinf(th);
}

// ---------------- RoPE on q (pre-scaled by log2e/sqrt(D)) and k; table-based ----------------
__global__ void rope_qk_kernel(const bf16* __restrict__ C, bf16* __restrict__ Qr, bf16* __restrict__ Kr,
                               const float* __restrict__ ct, const float* __restrict__ st) {
    const int idx = blockIdx.x * 256 + threadIdx.x;
    const int NQ = 2048 * 32 * 64;
    const float QSC = 0.12751743561884394f;        // (1/sqrt(128)) * log2(e)
    if (idx < NQ) {
        const int f = idx & 63;
        const int t = idx >> 6;
        const int h = t & 31;
        const int s = t >> 5;
        const float x1 = (float)C[(size_t)s * 6144 + h * 128 + f];
        const float x2 = (float)C[(size_t)s * 6144 + h * 128 + f + 64];
        const float cs = ct[(s << 6) + f], sn = st[(s << 6) + f];
        bf16* dst = Qr + ((size_t)h * 2048 + s) * 128 + f;
        dst[0]  = (bf16)((x1 * cs - x2 * sn) * QSC);
        dst[64] = (bf16)((x2 * cs + x1 * sn) * QSC);
    } else {
        const int i2 = idx - NQ;
        const int f = i2 & 63;
        const int t = i2 >> 6;
        const int h = t & 7;
        const int s = t >> 3;
        const float x1 = (float)C[(size_t)s * 6144 + 4096 + h * 128 + f];
        const float x2 = (float)C[(size_t)s * 6144 + 4096 + h * 128 + f + 64];
        const float cs = ct[(s << 6) + f], sn = st[(s << 6) + f];
        bf16* dst = Kr + ((size_t)h * 2048 + s) * 128 + f;
        dst[0]  = (bf16)(x1 * cs - x2 * sn);
        dst[64] = (bf16)(x2 * cs + x1 * sn);
    }
}

// ---------------- V transpose: C_qkv v-cols -> Vt[hkv][d=128][s=2048] ----------------
__global__ void transpose_v_kernel(const bf16* __restrict__ C, bf16* __restrict__ Vt) {
    __shared__ __align__(16) unsigned short t[64][136];
    const int hkv = blockIdx.x >> 5;
    const int st = blockIdx.x & 31;
    const int s0 = st * 64;
    const int tid = threadIdx.x;
#pragma unroll
    for (int it = 0; it < 4; ++it) {
        const int l = it * 2048 + tid * 8;
        const int r = l >> 7, c = l & 127;
        *(bf16x8*)&t[r][c] = *(const bf16x8*)&C[(size_t)(s0 + r) * 6144 + 5120 + hkv * 128 + c];
    }
    __syncthreads();
#pragma unroll
    for (int it = 0; it < 8; ++it) {
        const int o = it * 1024 + tid * 4;
        const int d = o >> 6, j = o & 63;
        ushort4 pk;
        pk.x = t[j + 0][d];
        pk.y = t[j + 1][d];
        pk.z = t[j + 2][d];
        pk.w = t[j + 3][d];
        *(ushort4*)&Vt[((size_t)hkv * 128 + d) * 2048 + s0 + j] = pk;
    }
}

// ---------------- causal GQA flash attention, equal-work persistent blocks (R6, proven) ----------------
// Grid 256 (1 block/CU). Block = 4 waves x 32 q-rows; sequential pair (15-a, a) =>
// uniform 17 KV-tiles (KVBLK=128) per block. K/V dbuf (144KB), 1 barrier/tile.
__launch_bounds__(256, 1)
__global__ void flash_attn_kernel(const bf16* __restrict__ Qr, const bf16* __restrict__ Kr,
                                  const bf16* __restrict__ Vt, bf16* __restrict__ Aout) {
    __shared__ __align__(16) bf16 Klds[2][128 * 128];
    __shared__ __align__(16) bf16 Vlds[2][128 * 128];
    __shared__ __align__(16) char Plds[4][4096];

    const int bid = blockIdx.x;
    const int hkv = bid & 7;
    const int r = bid >> 3;
    const int h = hkv * 4 + (r & 3);
    const int pa = r >> 2;
    const int qbA = 15 - pa, qbB = pa;
    const int tid = threadIdx.x;
    const int wave = tid >> 6, lane = tid & 63;
    const int laneR = lane & 15;
    const int laneS = lane >> 4;
    const int laneK = laneS * 8;
    const int rbase = laneS * 4;

    const bf16* Kh = Kr + (size_t)hkv * 2048 * 128;
    const bf16* Vh = Vt + (size_t)hkv * 128 * 2048;
    char* Pw = Plds[wave];

    auto stageK = [&](int kv0, int buf) {
#pragma unroll
        for (int s = 0; s < 8; ++s) {
            const int chunk = wave * 8 + s;
            const int L = chunk * 64 + lane;
            const int row = L >> 4, sl = L & 15;
            gld_lds16(Kh + (size_t)(kv0 + row) * 128 + ((sl ^ (row & 7)) << 3),
                      &Klds[buf][chunk * 512]);
        }
    };
    auto stageV = [&](int kv0, int buf) {
#pragma unroll
        for (int s = 0; s < 8; ++s) {
            const int chunk = wave * 8 + s;
            const int L = chunk * 64 + lane;
            const int row = L >> 4, sl = L & 15;
            gld_lds16(Vh + (size_t)row * 2048 + kv0 + ((sl ^ (row & 7)) << 3),
                      &Vlds[buf][chunk * 512]);
        }
    };

    int qbcur = qbA;
    int q0w = qbA * 128 + wave * 32;
    int tloc = 0;

    bf16x8 qf[2][4];
    auto loadQ = [&]() {
#pragma unroll
        for (int mi = 0; mi < 2; ++mi)
#pragma unroll
            for (int kc = 0; kc < 4; ++kc)
                qf[mi][kc] = *(const bf16x8*)&Qr[((size_t)h * 2048 + q0w + mi * 16 + laneR) * 128 + kc * 32 + laneK];
    };
    loadQ();

    f32x4 o[2][8] = {};
    float mrow[2][4], lrow[2][4];
#pragma unroll
    for (int mi = 0; mi < 2; ++mi)
#pragma unroll
        for (int rr = 0; rr < 4; ++rr) { mrow[mi][rr] = -1e30f; lrow[mi][rr] = 0.f; }

    stageK(0, 0);
    stageV(0, 0);
    __syncthreads();

    for (int g = 0; g < 17; ++g) {
        const int buf = g & 1;
        if (g < 16) {
            const int tn = (g + 1 <= qbA) ? (g + 1) : (g - qbA);
            stageK(tn * 128, buf ^ 1);
            stageV(tn * 128, buf ^ 1);
        }
        const int kv0 = tloc * 128;

        f32x4 sc[2][8] = {};
        __builtin_amdgcn_s_setprio(1);
#pragma unroll
        for (int kc = 0; kc < 4; ++kc) {
            bf16x8 kf[8];
#pragma unroll
            for (int j = 0; j < 8; ++j) {
                const int row = j * 16 + laneR;
                kf[j] = *(const bf16x8*)((const char*)Klds[buf] + row * 256 +
                                         ((kc * 64 + laneS * 16) ^ ((row & 7) << 4)));
            }
#pragma unroll
            for (int mi = 0; mi < 2; ++mi)
#pragma unroll
                for (int j = 0; j < 8; ++j)
                    sc[mi][j] = __builtin_amdgcn_mfma_f32_16x16x32_bf16(qf[mi][kc], kf[j], sc[mi][j], 0, 0, 0);
        }
        __builtin_amdgcn_s_setprio(0);

        if (tloc == qbcur) {
#pragma unroll
            for (int mi = 0; mi < 2; ++mi)
#pragma unroll
                for (int j = 0; j < 8; ++j)
#pragma unroll
                    for (int rr = 0; rr < 4; ++rr) {
                        const int qr = q0w + mi * 16 + rbase + rr;
                        const int kr = kv0 + j * 16 + laneR;
                        if (kr > qr) sc[mi][j][rr] = -1e30f;
                    }
        }

#pragma unroll
        for (int mi = 0; mi < 2; ++mi) {
#pragma unroll
            for (int rr = 0; rr < 4; ++rr) {
                float v = sc[mi][0][rr];
#pragma unroll
                for (int j = 1; j < 8; ++j) v = fmaxf(v, sc[mi][j][rr]);
                v = fmaxf(v, __shfl_xor(v, 1, 64));
                v = fmaxf(v, __shfl_xor(v, 2, 64));
                v = fmaxf(v, __shfl_xor(v, 4, 64));
                v = fmaxf(v, __shfl_xor(v, 8, 64));
                float m0 = mrow[mi][rr];
                if (v - m0 > 8.0f) {
                    const float fac = __builtin_exp2f(m0 - v);
                    mrow[mi][rr] = v;
                    m0 = v;
                    lrow[mi][rr] *= fac;
#pragma unroll
                    for (int j = 0; j < 8; ++j) o[mi][j][rr] *= fac;
                }
                float rs = 0.f;
#pragma unroll
                for (int j = 0; j < 8; ++j) {
                    const float p = __builtin_exp2f(sc[mi][j][rr] - m0);
                    sc[mi][j][rr] = p;
                    rs += p;
                }
                rs += __shfl_xor(rs, 1, 64);
                rs += __shfl_xor(rs, 2, 64);
                rs += __shfl_xor(rs, 4, 64);
                rs += __shfl_xor(rs, 8, 64);
                lrow[mi][rr] += rs;
            }
        }

#pragma unroll
        for (int hf = 0; hf < 2; ++hf) {
#pragma unroll
            for (int mi = 0; mi < 2; ++mi)
#pragma unroll
                for (int j = 0; j < 4; ++j)
#pragma unroll
                    for (int rr = 0; rr < 4; ++rr) {
                        const int row = mi * 16 + rbase + rr;
                        *(bf16*)(Pw + row * 128 + ((j * 32 + laneR * 2) ^ ((row & 7) << 4))) =
                            (bf16)sc[mi][hf * 4 + j][rr];
                    }
            __builtin_amdgcn_s_setprio(1);
#pragma unroll
            for (int kc = 0; kc < 2; ++kc) {
                bf16x8 pf[2];
#pragma unroll
                for (int mi = 0; mi < 2; ++mi) {
                    const int row = mi * 16 + laneR;
                    pf[mi] = *(const bf16x8*)(Pw + row * 128 + ((kc * 64 + laneS * 16) ^ ((row & 7) << 4)));
                }
                const int kcg = hf * 2 + kc;
                bf16x8 vf[8];
#pragma unroll
                for (int j = 0; j < 8; ++j) {
                    const int row = j * 16 + laneR;
                    vf[j] = *(const bf16x8*)((const char*)Vlds[buf] + row * 256 +
                                             ((kcg * 64 + laneS * 16) ^ ((row & 7) << 4)));
                }
#pragma unroll
                for (int mi = 0; mi < 2; ++mi)
#pragma unroll
                    for (int j = 0; j < 8; ++j)
                        o[mi][j] = __builtin_amdgcn_mfma_f32_16x16x32_bf16(pf[mi], vf[j], o[mi][j], 0, 0, 0);
            }
            __builtin_amdgcn_s_setprio(0);
        }

        if (tloc == qbcur) {
#pragma unroll
            for (int mi = 0; mi < 2; ++mi) {
                float rinv[4];
#pragma unroll
                for (int rr = 0; rr < 4; ++rr) rinv[rr] = 1.0f / lrow[mi][rr];
#pragma unroll
                for (int j = 0; j < 8; ++j)
#pragma unroll
                    for (int rr = 0; rr < 4; ++rr) {
                        const size_t row = (size_t)q0w + mi * 16 + rbase + rr;
                        Aout[row * 4096 + h * 128 + j * 16 + laneR] = (bf16)(o[mi][j][rr] * rinv[rr]);
                    }
            }
            if (g < 16) {
                qbcur = qbB;
                q0w = qbB * 128 + wave * 32;
                tloc = 0;
                loadQ();
#pragma unroll
                for (int mi = 0; mi < 2; ++mi)
#pragma unroll
                    for (int rr = 0; rr < 4; ++rr) { mrow[mi][rr] = -1e30f; lrow[mi][rr] = 0.f; }
#pragma unroll
                for (int mi = 0; mi < 2; ++mi)
#pragma unroll
                    for (int j = 0; j < 8; ++j)
                        o[mi][j] = f32x4{0.f, 0.f, 0.f, 0.f};
            }
        } else {
            ++tloc;
        }

        __syncthreads();
    }
}

// ---------------- launch ----------------
extern "C" void kernel_launch(void* const* d_in, const int* in_sizes, int n_in,
                              void* d_out, int out_size, void* d_ws, size_t ws_size,
                              hipStream_t stream) {
    const float* hidden = (const float*)d_in[0];
    const float* Wq = (const float*)d_in[1];
    const float* Wk = (const float*)d_in[2];
    const float* Wv = (const float*)d_in[3];
    const float* Wo = (const float*)d_in[4];
    float* out = (float*)d_out;
    char* ws = (char*)d_ws;

    // workspace layout (bytes):
    bf16* hs = (bf16*)(ws + 0);                 // [2048][4096]        16 MiB (dead after QKV)
    bf16* Wb = (bf16*)(ws + 16777216);          // [10240][4096]       80 MiB (Wq|Wk|Wv|Wo)
    bf16* Cq = (bf16*)(ws + 100663296);         // [2048][6144]        24 MiB
    bf16* Qr = (bf16*)(ws + 125829120);         // [32][2048][128]     16 MiB
    bf16* Kr = (bf16*)(ws + 142606336);         // [8][2048][128]       4 MiB
    bf16* Vt = (bf16*)(ws + 146800640);         // [8][128][2048]       4 MiB
    bf16* At = (bf16*)(ws + 150994944);         // [2048][4096]        16 MiB
    float* ct = (float*)(ws + 0);               // rope cos table (aliases dead hs)
    float* st = (float*)(ws + 524288);          // rope sin table
    (void)ws_size; (void)in_sizes; (void)n_in; (void)out_size;

    // 1. fused casts
    cvt_all_kernel<<<49152, 256, 0, stream>>>((const float4*)hidden, (const float4*)Wq,
                                              (const float4*)Wk, (const float4*)Wv,
                                              (const float4*)Wo, (ushort4*)hs, (ushort4*)Wb);

    // 2. fused QKV projection: ring + swizzle, 128x384 tiles -> 256 blocks (100% fill)
    gemm8p_kernel<384, false><<<dim3(16, 16), 512, 0, stream>>>(hs, Wb, Cq, 2048, 6144, 4096);

    // 3. rope tables + RoPE
    rope_table_kernel<<<512, 256, 0, stream>>>(ct, st);
    rope_qk_kernel<<<20480, 256, 0, stream>>>(Cq, Qr, Kr, ct, st);

    // 4. V transpose -> [hkv][d][s]
    transpose_v_kernel<<<256, 256, 0, stream>>>(Cq, Vt);

    // 5. causal GQA flash attention (R6 equal-work persistent, 256 blocks)
    flash_attn_kernel<<<256, 256, 0, stream>>>(Qr, Kr, Vt, At);

    // 6. output projection (ring + swizzle, 128x256 -> 256 blocks)
    gemm8p_kernel<256, true><<<dim3(16, 16), 512, 0, stream>>>(At, Wb + 25165824, out, 2048, 4096, 4096);
}

// Round 13
// 319.923 us; speedup vs baseline: 1.1841x; 1.0606x over previous
//
#include <hip/hip_runtime.h>

#define AS1 __attribute__((address_space(1)))
#define AS3 __attribute__((address_space(3)))

typedef __bf16 bf16;
typedef __bf16 bf16x8 __attribute__((ext_vector_type(8)));
typedef float f32x4 __attribute__((ext_vector_type(4)));

__device__ __forceinline__ void gld_lds16(const bf16* g, bf16* l) {
    __builtin_amdgcn_global_load_lds((const AS1 void*)g, (AS3 void*)l, 16, 0, 0);
}

#define SB0 __builtin_amdgcn_sched_barrier(0)

// ---------------- fused fp32 -> bf16 cast (all 5 tensors, one launch) ----------------
__global__ void cvt_all_kernel(const float4* __restrict__ h, const float4* __restrict__ wq,
                               const float4* __restrict__ wk, const float4* __restrict__ wv,
                               const float4* __restrict__ wo, ushort4* __restrict__ hs,
                               ushort4* __restrict__ wb) {
    const int i = blockIdx.x * 256 + threadIdx.x;   // 0 .. 12582911
    const float4* src;
    ushort4* dst;
    if (i < 2097152)      { src = h  + i;             dst = hs + i; }
    else if (i < 6291456) { src = wq + (i - 2097152); dst = wb + (i - 2097152); }
    else if (i < 7340032) { src = wk + (i - 6291456); dst = wb + 4194304 + (i - 6291456); }
    else if (i < 8388608) { src = wv + (i - 7340032); dst = wb + 5242880 + (i - 7340032); }
    else                  { src = wo + (i - 8388608); dst = wb + 6291456 + (i - 8388608); }
    const float4 v = *src;
    ushort4 r;
    r.x = __builtin_bit_cast(unsigned short, (bf16)v.x);
    r.y = __builtin_bit_cast(unsigned short, (bf16)v.y);
    r.z = __builtin_bit_cast(unsigned short, (bf16)v.z);
    r.w = __builtin_bit_cast(unsigned short, (bf16)v.w);
    *dst = r;
}

// ---------------- GEMM: counted-vmcnt 4-slot ring + conflict-free slot-XOR swizzle (R12, frozen) ----------------
template <int BN, bool OUTF32>
__launch_bounds__(512, 2)
__global__ void gemm8p_kernel(const bf16* __restrict__ A, const bf16* __restrict__ W,
                              void* __restrict__ Cout, int M, int N, int K) {
    constexpr int NF = BN / 64;
    constexpr int IB = BN / 128;
    __shared__ __align__(16) bf16 Asl[4][128 * 32];
    __shared__ __align__(16) bf16 Bsl[4][BN * 32];

    const int tn = blockIdx.x * BN;
    const int tm = blockIdx.y * 128;
    const int tid = threadIdx.x;
    const int wave = tid >> 6;
    const int lane = tid & 63;
    const int laneR = lane & 15;
    const int laneS = lane >> 4;
    const int wmB = (wave >> 2) * 64;
    const int wnB = (wave & 3) * (BN / 4);
    const int NT = K >> 5;
    const int sofs = (laneS ^ ((laneR >> 1) & 3)) << 3;

    auto stage = [&](int t) {
        const int slot = t & 3;
        const int k0 = t << 5;
        {
            const int row = tid >> 2, g = tid & 3;
            const int sg = g ^ ((row >> 1) & 3);
            gld_lds16(A + (size_t)(tm + row) * K + k0 + sg * 8, &Asl[slot][wave * 512]);
        }
#pragma unroll
        for (int i = 0; i < IB; ++i) {
            const int row = i * 128 + (tid >> 2), g = tid & 3;
            const int sg = g ^ ((row >> 1) & 3);
            gld_lds16(W + (size_t)(tn + row) * K + k0 + sg * 8,
                      &Bsl[slot][i * 4096 + wave * 512]);
        }
    };

    f32x4 acc[4][NF] = {};

    stage(0); stage(1); stage(2);
    if constexpr (BN == 384) asm volatile("s_waitcnt vmcnt(8)" ::: "memory");
    else                     asm volatile("s_waitcnt vmcnt(6)" ::: "memory");
    SB0;
    __builtin_amdgcn_s_barrier();
    SB0;

    for (int t = 0; t < NT; ++t) {
        const int slot = t & 3;
        bf16x8 af[4], bfr[NF];
#pragma unroll
        for (int mf = 0; mf < 4; ++mf)
            af[mf] = *(const bf16x8*)&Asl[slot][(wmB + mf * 16 + laneR) * 32 + sofs];
#pragma unroll
        for (int nf = 0; nf < NF; ++nf)
            bfr[nf] = *(const bf16x8*)&Bsl[slot][(wnB + nf * 16 + laneR) * 32 + sofs];

        if (t + 3 < NT) stage(t + 3);

#pragma unroll
        for (int mf = 0; mf < 4; ++mf)
#pragma unroll
            for (int nf = 0; nf < NF; ++nf)
                acc[mf][nf] = __builtin_amdgcn_mfma_f32_16x16x32_bf16(af[mf], bfr[nf], acc[mf][nf], 0, 0, 0);

        SB0;
        if (t + 3 < NT) {
            if constexpr (BN == 384) asm volatile("s_waitcnt vmcnt(8)" ::: "memory");
            else                     asm volatile("s_waitcnt vmcnt(6)" ::: "memory");
        } else if (t + 3 == NT) {
            if constexpr (BN == 384) asm volatile("s_waitcnt vmcnt(4)" ::: "memory");
            else                     asm volatile("s_waitcnt vmcnt(3)" ::: "memory");
        } else {
            asm volatile("s_waitcnt vmcnt(0)" ::: "memory");
        }
        SB0;
        __builtin_amdgcn_s_barrier();
        SB0;
    }

    const int rbase = laneS * 4;
#pragma unroll
    for (int mf = 0; mf < 4; ++mf)
#pragma unroll
        for (int nf = 0; nf < NF; ++nf)
#pragma unroll
            for (int rr = 0; rr < 4; ++rr) {
                const size_t row = (size_t)tm + wmB + mf * 16 + rbase + rr;
                const size_t col = (size_t)tn + wnB + nf * 16 + laneR;
                if constexpr (OUTF32) ((float*)Cout)[row * N + col] = acc[mf][nf][rr];
                else                  ((bf16*)Cout)[row * N + col] = (bf16)acc[mf][nf][rr];
            }
    (void)M;
}

// ---------------- RoPE cos/sin table gen ----------------
__global__ void rope_table_kernel(float* __restrict__ ct, float* __restrict__ st) {
    const int idx = blockIdx.x * 256 + threadIdx.x;
    const int f = idx & 63;
    const int s = idx >> 6;
    const float th = s * expf(-0.14391156831212787f * (float)f);
    ct[idx] = cosf(th);
    st[idx] = sinf(th);
}

// ---------------- RoPE on q (pre-scaled by log2e/sqrt(D)) and k; table-based ----------------
__global__ void rope_qk_kernel(const bf16* __restrict__ C, bf16* __restrict__ Qr, bf16* __restrict__ Kr,
                               const float* __restrict__ ct, const float* __restrict__ st) {
    const int idx = blockIdx.x * 256 + threadIdx.x;
    const int NQ = 2048 * 32 * 64;
    const float QSC = 0.12751743561884394f;        // (1/sqrt(128)) * log2(e)
    if (idx < NQ) {
        const int f = idx & 63;
        const int t = idx >> 6;
        const int h = t & 31;
        const int s = t >> 5;
        const float x1 = (float)C[(size_t)s * 6144 + h * 128 + f];
        const float x2 = (float)C[(size_t)s * 6144 + h * 128 + f + 64];
        const float cs = ct[(s << 6) + f], sn = st[(s << 6) + f];
        bf16* dst = Qr + ((size_t)h * 2048 + s) * 128 + f;
        dst[0]  = (bf16)((x1 * cs - x2 * sn) * QSC);
        dst[64] = (bf16)((x2 * cs + x1 * sn) * QSC);
    } else {
        const int i2 = idx - NQ;
        const int f = i2 & 63;
        const int t = i2 >> 6;
        const int h = t & 7;
        const int s = t >> 3;
        const float x1 = (float)C[(size_t)s * 6144 + 4096 + h * 128 + f];
        const float x2 = (float)C[(size_t)s * 6144 + 4096 + h * 128 + f + 64];
        const float cs = ct[(s << 6) + f], sn = st[(s << 6) + f];
        bf16* dst = Kr + ((size_t)h * 2048 + s) * 128 + f;
        dst[0]  = (bf16)(x1 * cs - x2 * sn);
        dst[64] = (bf16)(x2 * cs + x1 * sn);
    }
}

// ---------------- V transpose: C_qkv v-cols -> Vt[hkv][d=128][s=2048] ----------------
__global__ void transpose_v_kernel(const bf16* __restrict__ C, bf16* __restrict__ Vt) {
    __shared__ __align__(16) unsigned short t[64][136];
    const int hkv = blockIdx.x >> 5;
    const int st = blockIdx.x & 31;
    const int s0 = st * 64;
    const int tid = threadIdx.x;
#pragma unroll
    for (int it = 0; it < 4; ++it) {
        const int l = it * 2048 + tid * 8;
        const int r = l >> 7, c = l & 127;
        *(bf16x8*)&t[r][c] = *(const bf16x8*)&C[(size_t)(s0 + r) * 6144 + 5120 + hkv * 128 + c];
    }
    __syncthreads();
#pragma unroll
    for (int it = 0; it < 8; ++it) {
        const int o = it * 1024 + tid * 4;
        const int d = o >> 6, j = o & 63;
        ushort4 pk;
        pk.x = t[j + 0][d];
        pk.y = t[j + 1][d];
        pk.z = t[j + 2][d];
        pk.w = t[j + 3][d];
        *(ushort4*)&Vt[((size_t)hkv * 128 + d) * 2048 + s0 + j] = pk;
    }
}

// ---------------- causal GQA flash attention: R6 structure, 8 waves (2/SIMD) ----------------
// Grid 256 (1 block/CU). Block = 512 thr = 8 waves x 16 q-rows = one 128-row q-block;
// sequential pair (15-a, a) => uniform 17 KV-tiles (KVBLK=128) per block. Identical
// staging addresses/swizzles/barrier schedule to the proven R6 kernel; the only change
// is the q-row partition (32 rows/wave -> 16 rows/wave) for 2 waves/SIMD latency hiding.
// LDS: K dbuf 2x32KB + V dbuf 2x32KB + P 8x2KB = 144KB.
__launch_bounds__(512, 1)
__global__ void flash_attn_kernel(const bf16* __restrict__ Qr, const bf16* __restrict__ Kr,
                                  const bf16* __restrict__ Vt, bf16* __restrict__ Aout) {
    __shared__ __align__(16) bf16 Klds[2][128 * 128];
    __shared__ __align__(16) bf16 Vlds[2][128 * 128];
    __shared__ __align__(16) char Plds[8][2048];

    const int bid = blockIdx.x;
    const int hkv = bid & 7;
    const int r = bid >> 3;
    const int h = hkv * 4 + (r & 3);
    const int pa = r >> 2;
    const int qbA = 15 - pa, qbB = pa;
    const int tid = threadIdx.x;
    const int wave = tid >> 6, lane = tid & 63;
    const int laneR = lane & 15;
    const int laneS = lane >> 4;
    const int laneK = laneS * 8;
    const int rbase = laneS * 4;

    const bf16* Kh = Kr + (size_t)hkv * 2048 * 128;
    const bf16* Vh = Vt + (size_t)hkv * 128 * 2048;
    char* Pw = Plds[wave];

    // stage 32KB tile as 32 chunks of 1KB; 8 waves x 4 issues (same addresses as R6)
    auto stageK = [&](int kv0, int buf) {
#pragma unroll
        for (int s = 0; s < 4; ++s) {
            const int chunk = wave * 4 + s;
            const int L = chunk * 64 + lane;
            const int row = L >> 4, sl = L & 15;
            gld_lds16(Kh + (size_t)(kv0 + row) * 128 + ((sl ^ (row & 7)) << 3),
                      &Klds[buf][chunk * 512]);
        }
    };
    auto stageV = [&](int kv0, int buf) {
#pragma unroll
        for (int s = 0; s < 4; ++s) {
            const int chunk = wave * 4 + s;
            const int L = chunk * 64 + lane;
            const int row = L >> 4, sl = L & 15;
            gld_lds16(Vh + (size_t)row * 2048 + kv0 + ((sl ^ (row & 7)) << 3),
                      &Vlds[buf][chunk * 512]);
        }
    };

    int qbcur = qbA;
    int q0w = qbA * 128 + wave * 16;
    int tloc = 0;

    bf16x8 qf[4];
    auto loadQ = [&]() {
#pragma unroll
        for (int kc = 0; kc < 4; ++kc)
            qf[kc] = *(const bf16x8*)&Qr[((size_t)h * 2048 + q0w + laneR) * 128 + kc * 32 + laneK];
    };
    loadQ();

    f32x4 o[8] = {};
    float mrow[4], lrow[4];
#pragma unroll
    for (int rr = 0; rr < 4; ++rr) { mrow[rr] = -1e30f; lrow[rr] = 0.f; }

    stageK(0, 0);
    stageV(0, 0);
    __syncthreads();

    for (int g = 0; g < 17; ++g) {
        const int buf = g & 1;
        if (g < 16) {
            const int tn = (g + 1 <= qbA) ? (g + 1) : (g - qbA);
            stageK(tn * 128, buf ^ 1);
            stageV(tn * 128, buf ^ 1);
        }
        const int kv0 = tloc * 128;

        // ---- scores = Q K^T (log2 domain) ----
        f32x4 sc[8] = {};
        __builtin_amdgcn_s_setprio(1);
#pragma unroll
        for (int kc = 0; kc < 4; ++kc) {
            bf16x8 kf[8];
#pragma unroll
            for (int j = 0; j < 8; ++j) {
                const int row = j * 16 + laneR;
                kf[j] = *(const bf16x8*)((const char*)Klds[buf] + row * 256 +
                                         ((kc * 64 + laneS * 16) ^ ((row & 7) << 4)));
            }
#pragma unroll
            for (int j = 0; j < 8; ++j)
                sc[j] = __builtin_amdgcn_mfma_f32_16x16x32_bf16(qf[kc], kf[j], sc[j], 0, 0, 0);
        }
        __builtin_amdgcn_s_setprio(0);

        if (tloc == qbcur) {       // diagonal tile: causal mask
#pragma unroll
            for (int j = 0; j < 8; ++j)
#pragma unroll
                for (int rr = 0; rr < 4; ++rr) {
                    const int qr = q0w + rbase + rr;
                    const int kr = kv0 + j * 16 + laneR;
                    if (kr > qr) sc[j][rr] = -1e30f;
                }
        }

        // ---- online softmax, defer-max (THR=8) ----
#pragma unroll
        for (int rr = 0; rr < 4; ++rr) {
            float v = sc[0][rr];
#pragma unroll
            for (int j = 1; j < 8; ++j) v = fmaxf(v, sc[j][rr]);
            v = fmaxf(v, __shfl_xor(v, 1, 64));
            v = fmaxf(v, __shfl_xor(v, 2, 64));
            v = fmaxf(v, __shfl_xor(v, 4, 64));
            v = fmaxf(v, __shfl_xor(v, 8, 64));
            float m0 = mrow[rr];
            if (v - m0 > 8.0f) {
                const float fac = __builtin_exp2f(m0 - v);
                mrow[rr] = v;
                m0 = v;
                lrow[rr] *= fac;
#pragma unroll
                for (int j = 0; j < 8; ++j) o[j][rr] *= fac;
            }
            float rs = 0.f;
#pragma unroll
            for (int j = 0; j < 8; ++j) {
                const float p = __builtin_exp2f(sc[j][rr] - m0);
                sc[j][rr] = p;
                rs += p;
            }
            rs += __shfl_xor(rs, 1, 64);
            rs += __shfl_xor(rs, 2, 64);
            rs += __shfl_xor(rs, 4, 64);
            rs += __shfl_xor(rs, 8, 64);
            lrow[rr] += rs;
        }

        // ---- P -> LDS and O += P V, in two 64-kv halves (wave-private 2KB buffer) ----
#pragma unroll
        for (int hf = 0; hf < 2; ++hf) {
#pragma unroll
            for (int j = 0; j < 4; ++j)
#pragma unroll
                for (int rr = 0; rr < 4; ++rr) {
                    const int row = rbase + rr;    // 0..15
                    *(bf16*)(Pw + row * 128 + ((j * 32 + laneR * 2) ^ ((row & 7) << 4))) =
                        (bf16)sc[hf * 4 + j][rr];
                }
            __builtin_amdgcn_s_setprio(1);
#pragma unroll
            for (int kc = 0; kc < 2; ++kc) {
                bf16x8 pf = *(const bf16x8*)(Pw + laneR * 128 +
                                             ((kc * 64 + laneS * 16) ^ ((laneR & 7) << 4)));
                const int kcg = hf * 2 + kc;
                bf16x8 vf[8];
#pragma unroll
                for (int j = 0; j < 8; ++j) {
                    const int row = j * 16 + laneR;
                    vf[j] = *(const bf16x8*)((const char*)Vlds[buf] + row * 256 +
                                             ((kcg * 64 + laneS * 16) ^ ((row & 7) << 4)));
                }
#pragma unroll
                for (int j = 0; j < 8; ++j)
                    o[j] = __builtin_amdgcn_mfma_f32_16x16x32_bf16(pf, vf[j], o[j], 0, 0, 0);
            }
            __builtin_amdgcn_s_setprio(0);
        }

        // ---- pass boundary: write out, reset, switch to light q-block ----
        if (tloc == qbcur) {
            float rinv[4];
#pragma unroll
            for (int rr = 0; rr < 4; ++rr) rinv[rr] = 1.0f / lrow[rr];
#pragma unroll
            for (int j = 0; j < 8; ++j)
#pragma unroll
                for (int rr = 0; rr < 4; ++rr) {
                    const size_t row = (size_t)q0w + rbase + rr;
                    Aout[row * 4096 + h * 128 + j * 16 + laneR] = (bf16)(o[j][rr] * rinv[rr]);
                }
            if (g < 16) {
                qbcur = qbB;
                q0w = qbB * 128 + wave * 16;
                tloc = 0;
                loadQ();
#pragma unroll
                for (int rr = 0; rr < 4; ++rr) { mrow[rr] = -1e30f; lrow[rr] = 0.f; }
#pragma unroll
                for (int j = 0; j < 8; ++j) o[j] = f32x4{0.f, 0.f, 0.f, 0.f};
            }
        } else {
            ++tloc;
        }

        __syncthreads();
    }
}

// ---------------- launch ----------------
extern "C" void kernel_launch(void* const* d_in, const int* in_sizes, int n_in,
                              void* d_out, int out_size, void* d_ws, size_t ws_size,
                              hipStream_t stream) {
    const float* hidden = (const float*)d_in[0];
    const float* Wq = (const float*)d_in[1];
    const float* Wk = (const float*)d_in[2];
    const float* Wv = (const float*)d_in[3];
    const float* Wo = (const float*)d_in[4];
    float* out = (float*)d_out;
    char* ws = (char*)d_ws;

    // workspace layout (bytes):
    bf16* hs = (bf16*)(ws + 0);                 // [2048][4096]        16 MiB (dead after QKV)
    bf16* Wb = (bf16*)(ws + 16777216);          // [10240][4096]       80 MiB (Wq|Wk|Wv|Wo)
    bf16* Cq = (bf16*)(ws + 100663296);         // [2048][6144]        24 MiB
    bf16* Qr = (bf16*)(ws + 125829120);         // [32][2048][128]     16 MiB
    bf16* Kr = (bf16*)(ws + 142606336);         // [8][2048][128]       4 MiB
    bf16* Vt = (bf16*)(ws + 146800640);         // [8][128][2048]       4 MiB
    bf16* At = (bf16*)(ws + 150994944);         // [2048][4096]        16 MiB
    float* ct = (float*)(ws + 0);               // rope cos table (aliases dead hs)
    float* st = (float*)(ws + 524288);          // rope sin table
    (void)ws_size; (void)in_sizes; (void)n_in; (void)out_size;

    // 1. fused casts
    cvt_all_kernel<<<49152, 256, 0, stream>>>((const float4*)hidden, (const float4*)Wq,
                                              (const float4*)Wk, (const float4*)Wv,
                                              (const float4*)Wo, (ushort4*)hs, (ushort4*)Wb);

    // 2. fused QKV projection: ring + swizzle, 128x384 tiles -> 256 blocks
    gemm8p_kernel<384, false><<<dim3(16, 16), 512, 0, stream>>>(hs, Wb, Cq, 2048, 6144, 4096);

    // 3. rope tables + RoPE
    rope_table_kernel<<<512, 256, 0, stream>>>(ct, st);
    rope_qk_kernel<<<20480, 256, 0, stream>>>(Cq, Qr, Kr, ct, st);

    // 4. V transpose -> [hkv][d][s]
    transpose_v_kernel<<<256, 256, 0, stream>>>(Cq, Vt);

    // 5. causal GQA flash attention (equal-work persistent, 256 blocks x 8 waves)
    flash_attn_kernel<<<256, 512, 0, stream>>>(Qr, Kr, Vt, At);

    // 6. output projection (ring + swizzle, 128x256 -> 256 blocks)
    gemm8p_kernel<256, true><<<dim3(16, 16), 512, 0, stream>>>(At, Wb + 25165824, out, 2048, 4096, 4096);
}

// Round 14
// 319.103 us; speedup vs baseline: 1.1872x; 1.0026x over previous
//
#include <hip/hip_runtime.h>

#define AS1 __attribute__((address_space(1)))
#define AS3 __attribute__((address_space(3)))

typedef __bf16 bf16;
typedef __bf16 bf16x8 __attribute__((ext_vector_type(8)));
typedef float f32x4 __attribute__((ext_vector_type(4)));

__device__ __forceinline__ void gld_lds16(const bf16* g, bf16* l) {
    __builtin_amdgcn_global_load_lds((const AS1 void*)g, (AS3 void*)l, 16, 0, 0);
}

#define SB0 __builtin_amdgcn_sched_barrier(0)

// ---------------- fused fp32 -> bf16 cast (all 5 tensors, grid-stride) ----------------
__global__ void cvt_all_kernel(const float4* __restrict__ h, const float4* __restrict__ wq,
                               const float4* __restrict__ wk, const float4* __restrict__ wv,
                               const float4* __restrict__ wo, ushort4* __restrict__ hs,
                               ushort4* __restrict__ wb) {
    for (int i = blockIdx.x * 256 + threadIdx.x; i < 12582912; i += 2048 * 256) {
        const float4* src;
        ushort4* dst;
        if (i < 2097152)      { src = h  + i;             dst = hs + i; }
        else if (i < 6291456) { src = wq + (i - 2097152); dst = wb + (i - 2097152); }
        else if (i < 7340032) { src = wk + (i - 6291456); dst = wb + 4194304 + (i - 6291456); }
        else if (i < 8388608) { src = wv + (i - 7340032); dst = wb + 5242880 + (i - 7340032); }
        else                  { src = wo + (i - 8388608); dst = wb + 6291456 + (i - 8388608); }
        const float4 v = *src;
        ushort4 r;
        r.x = __builtin_bit_cast(unsigned short, (bf16)v.x);
        r.y = __builtin_bit_cast(unsigned short, (bf16)v.y);
        r.z = __builtin_bit_cast(unsigned short, (bf16)v.z);
        r.w = __builtin_bit_cast(unsigned short, (bf16)v.w);
        *dst = r;
    }
}

// ---------------- GEMM: counted-vmcnt 4-slot ring + conflict-free slot-XOR swizzle (frozen) ----------------
template <int BN, bool OUTF32>
__launch_bounds__(512, 2)
__global__ void gemm8p_kernel(const bf16* __restrict__ A, const bf16* __restrict__ W,
                              void* __restrict__ Cout, int M, int N, int K) {
    constexpr int NF = BN / 64;
    constexpr int IB = BN / 128;
    __shared__ __align__(16) bf16 Asl[4][128 * 32];
    __shared__ __align__(16) bf16 Bsl[4][BN * 32];

    const int tn = blockIdx.x * BN;
    const int tm = blockIdx.y * 128;
    const int tid = threadIdx.x;
    const int wave = tid >> 6;
    const int lane = tid & 63;
    const int laneR = lane & 15;
    const int laneS = lane >> 4;
    const int wmB = (wave >> 2) * 64;
    const int wnB = (wave & 3) * (BN / 4);
    const int NT = K >> 5;
    const int sofs = (laneS ^ ((laneR >> 1) & 3)) << 3;

    auto stage = [&](int t) {
        const int slot = t & 3;
        const int k0 = t << 5;
        {
            const int row = tid >> 2, g = tid & 3;
            const int sg = g ^ ((row >> 1) & 3);
            gld_lds16(A + (size_t)(tm + row) * K + k0 + sg * 8, &Asl[slot][wave * 512]);
        }
#pragma unroll
        for (int i = 0; i < IB; ++i) {
            const int row = i * 128 + (tid >> 2), g = tid & 3;
            const int sg = g ^ ((row >> 1) & 3);
            gld_lds16(W + (size_t)(tn + row) * K + k0 + sg * 8,
                      &Bsl[slot][i * 4096 + wave * 512]);
        }
    };

    f32x4 acc[4][NF] = {};

    stage(0); stage(1); stage(2);
    if constexpr (BN == 384) asm volatile("s_waitcnt vmcnt(8)" ::: "memory");
    else                     asm volatile("s_waitcnt vmcnt(6)" ::: "memory");
    SB0;
    __builtin_amdgcn_s_barrier();
    SB0;

    for (int t = 0; t < NT; ++t) {
        const int slot = t & 3;
        bf16x8 af[4], bfr[NF];
#pragma unroll
        for (int mf = 0; mf < 4; ++mf)
            af[mf] = *(const bf16x8*)&Asl[slot][(wmB + mf * 16 + laneR) * 32 + sofs];
#pragma unroll
        for (int nf = 0; nf < NF; ++nf)
            bfr[nf] = *(const bf16x8*)&Bsl[slot][(wnB + nf * 16 + laneR) * 32 + sofs];

        if (t + 3 < NT) stage(t + 3);

#pragma unroll
        for (int mf = 0; mf < 4; ++mf)
#pragma unroll
            for (int nf = 0; nf < NF; ++nf)
                acc[mf][nf] = __builtin_amdgcn_mfma_f32_16x16x32_bf16(af[mf], bfr[nf], acc[mf][nf], 0, 0, 0);

        SB0;
        if (t + 3 < NT) {
            if constexpr (BN == 384) asm volatile("s_waitcnt vmcnt(8)" ::: "memory");
            else                     asm volatile("s_waitcnt vmcnt(6)" ::: "memory");
        } else if (t + 3 == NT) {
            if constexpr (BN == 384) asm volatile("s_waitcnt vmcnt(4)" ::: "memory");
            else                     asm volatile("s_waitcnt vmcnt(3)" ::: "memory");
        } else {
            asm volatile("s_waitcnt vmcnt(0)" ::: "memory");
        }
        SB0;
        __builtin_amdgcn_s_barrier();
        SB0;
    }

    const int rbase = laneS * 4;
#pragma unroll
    for (int mf = 0; mf < 4; ++mf)
#pragma unroll
        for (int nf = 0; nf < NF; ++nf)
#pragma unroll
            for (int rr = 0; rr < 4; ++rr) {
                const size_t row = (size_t)tm + wmB + mf * 16 + rbase + rr;
                const size_t col = (size_t)tn + wnB + nf * 16 + laneR;
                if constexpr (OUTF32) ((float*)Cout)[row * N + col] = acc[mf][nf][rr];
                else                  ((bf16*)Cout)[row * N + col] = (bf16)acc[mf][nf][rr];
            }
    (void)M;
}

// ---------------- RoPE cos/sin table gen ----------------
__global__ void rope_table_kernel(float* __restrict__ ct, float* __restrict__ st) {
    const int idx = blockIdx.x * 256 + threadIdx.x;
    const int f = idx & 63;
    const int s = idx >> 6;
    const float th = s * expf(-0.14391156831212787f * (float)f);
    ct[idx] = cosf(th);
    st[idx] = sinf(th);
}

// ---------------- fused RoPE (q,k) + V transpose, block-ranged ----------------
// blocks 0..20479: rope on q (scaled by log2e/sqrt(D)) and k -> Qr/Kr [h][s][d]
// blocks 20480..20735: V transpose -> Vt [hkv][d=128][s=2048]
__global__ void rope_tv_kernel(const bf16* __restrict__ C, bf16* __restrict__ Qr,
                               bf16* __restrict__ Kr, bf16* __restrict__ Vt,
                               const float* __restrict__ ct, const float* __restrict__ st) {
    __shared__ __align__(16) unsigned short tbuf[64][136];
    const int bid = blockIdx.x;
    const int tid = threadIdx.x;
    if (bid < 20480) {
        const int idx = bid * 256 + tid;
        const int NQ = 2048 * 32 * 64;
        const float QSC = 0.12751743561884394f;        // (1/sqrt(128)) * log2(e)
        if (idx < NQ) {
            const int f = idx & 63;
            const int t = idx >> 6;
            const int h = t & 31;
            const int s = t >> 5;
            const float x1 = (float)C[(size_t)s * 6144 + h * 128 + f];
            const float x2 = (float)C[(size_t)s * 6144 + h * 128 + f + 64];
            const float cs = ct[(s << 6) + f], sn = st[(s << 6) + f];
            bf16* dst = Qr + ((size_t)h * 2048 + s) * 128 + f;
            dst[0]  = (bf16)((x1 * cs - x2 * sn) * QSC);
            dst[64] = (bf16)((x2 * cs + x1 * sn) * QSC);
        } else {
            const int i2 = idx - NQ;
            const int f = i2 & 63;
            const int t = i2 >> 6;
            const int h = t & 7;
            const int s = t >> 3;
            const float x1 = (float)C[(size_t)s * 6144 + 4096 + h * 128 + f];
            const float x2 = (float)C[(size_t)s * 6144 + 4096 + h * 128 + f + 64];
            const float cs = ct[(s << 6) + f], sn = st[(s << 6) + f];
            bf16* dst = Kr + ((size_t)h * 2048 + s) * 128 + f;
            dst[0]  = (bf16)(x1 * cs - x2 * sn);
            dst[64] = (bf16)(x2 * cs + x1 * sn);
        }
    } else {
        const int b2 = bid - 20480;                  // 0..255
        const int hkv = b2 >> 5;
        const int st8 = b2 & 31;
        const int s0 = st8 * 64;
#pragma unroll
        for (int it = 0; it < 4; ++it) {
            const int l = it * 2048 + tid * 8;
            const int r = l >> 7, c = l & 127;
            *(bf16x8*)&tbuf[r][c] = *(const bf16x8*)&C[(size_t)(s0 + r) * 6144 + 5120 + hkv * 128 + c];
        }
        __syncthreads();
#pragma unroll
        for (int it = 0; it < 8; ++it) {
            const int o = it * 1024 + tid * 4;
            const int d = o >> 6, j = o & 63;
            ushort4 pk;
            pk.x = tbuf[j + 0][d];
            pk.y = tbuf[j + 1][d];
            pk.z = tbuf[j + 2][d];
            pk.w = tbuf[j + 3][d];
            *(ushort4*)&Vt[((size_t)hkv * 128 + d) * 2048 + s0 + j] = pk;
        }
    }
}

// ---------------- causal GQA flash attention: equal-work persistent, 8 waves (R13, frozen) ----------------
__launch_bounds__(512, 1)
__global__ void flash_attn_kernel(const bf16* __restrict__ Qr, const bf16* __restrict__ Kr,
                                  const bf16* __restrict__ Vt, bf16* __restrict__ Aout) {
    __shared__ __align__(16) bf16 Klds[2][128 * 128];
    __shared__ __align__(16) bf16 Vlds[2][128 * 128];
    __shared__ __align__(16) char Plds[8][2048];

    const int bid = blockIdx.x;
    const int hkv = bid & 7;
    const int r = bid >> 3;
    const int h = hkv * 4 + (r & 3);
    const int pa = r >> 2;
    const int qbA = 15 - pa, qbB = pa;
    const int tid = threadIdx.x;
    const int wave = tid >> 6, lane = tid & 63;
    const int laneR = lane & 15;
    const int laneS = lane >> 4;
    const int laneK = laneS * 8;
    const int rbase = laneS * 4;

    const bf16* Kh = Kr + (size_t)hkv * 2048 * 128;
    const bf16* Vh = Vt + (size_t)hkv * 128 * 2048;
    char* Pw = Plds[wave];

    auto stageK = [&](int kv0, int buf) {
#pragma unroll
        for (int s = 0; s < 4; ++s) {
            const int chunk = wave * 4 + s;
            const int L = chunk * 64 + lane;
            const int row = L >> 4, sl = L & 15;
            gld_lds16(Kh + (size_t)(kv0 + row) * 128 + ((sl ^ (row & 7)) << 3),
                      &Klds[buf][chunk * 512]);
        }
    };
    auto stageV = [&](int kv0, int buf) {
#pragma unroll
        for (int s = 0; s < 4; ++s) {
            const int chunk = wave * 4 + s;
            const int L = chunk * 64 + lane;
            const int row = L >> 4, sl = L & 15;
            gld_lds16(Vh + (size_t)row * 2048 + kv0 + ((sl ^ (row & 7)) << 3),
                      &Vlds[buf][chunk * 512]);
        }
    };

    int qbcur = qbA;
    int q0w = qbA * 128 + wave * 16;
    int tloc = 0;

    bf16x8 qf[4];
    auto loadQ = [&]() {
#pragma unroll
        for (int kc = 0; kc < 4; ++kc)
            qf[kc] = *(const bf16x8*)&Qr[((size_t)h * 2048 + q0w + laneR) * 128 + kc * 32 + laneK];
    };
    loadQ();

    f32x4 o[8] = {};
    float mrow[4], lrow[4];
#pragma unroll
    for (int rr = 0; rr < 4; ++rr) { mrow[rr] = -1e30f; lrow[rr] = 0.f; }

    stageK(0, 0);
    stageV(0, 0);
    __syncthreads();

    for (int g = 0; g < 17; ++g) {
        const int buf = g & 1;
        if (g < 16) {
            const int tn = (g + 1 <= qbA) ? (g + 1) : (g - qbA);
            stageK(tn * 128, buf ^ 1);
            stageV(tn * 128, buf ^ 1);
        }
        const int kv0 = tloc * 128;

        f32x4 sc[8] = {};
        __builtin_amdgcn_s_setprio(1);
#pragma unroll
        for (int kc = 0; kc < 4; ++kc) {
            bf16x8 kf[8];
#pragma unroll
            for (int j = 0; j < 8; ++j) {
                const int row = j * 16 + laneR;
                kf[j] = *(const bf16x8*)((const char*)Klds[buf] + row * 256 +
                                         ((kc * 64 + laneS * 16) ^ ((row & 7) << 4)));
            }
#pragma unroll
            for (int j = 0; j < 8; ++j)
                sc[j] = __builtin_amdgcn_mfma_f32_16x16x32_bf16(qf[kc], kf[j], sc[j], 0, 0, 0);
        }
        __builtin_amdgcn_s_setprio(0);

        if (tloc == qbcur) {
#pragma unroll
            for (int j = 0; j < 8; ++j)
#pragma unroll
                for (int rr = 0; rr < 4; ++rr) {
                    const int qr = q0w + rbase + rr;
                    const int kr = kv0 + j * 16 + laneR;
                    if (kr > qr) sc[j][rr] = -1e30f;
                }
        }

#pragma unroll
        for (int rr = 0; rr < 4; ++rr) {
            float v = sc[0][rr];
#pragma unroll
            for (int j = 1; j < 8; ++j) v = fmaxf(v, sc[j][rr]);
            v = fmaxf(v, __shfl_xor(v, 1, 64));
            v = fmaxf(v, __shfl_xor(v, 2, 64));
            v = fmaxf(v, __shfl_xor(v, 4, 64));
            v = fmaxf(v, __shfl_xor(v, 8, 64));
            float m0 = mrow[rr];
            if (v - m0 > 8.0f) {
                const float fac = __builtin_exp2f(m0 - v);
                mrow[rr] = v;
                m0 = v;
                lrow[rr] *= fac;
#pragma unroll
                for (int j = 0; j < 8; ++j) o[j][rr] *= fac;
            }
            float rs = 0.f;
#pragma unroll
            for (int j = 0; j < 8; ++j) {
                const float p = __builtin_exp2f(sc[j][rr] - m0);
                sc[j][rr] = p;
                rs += p;
            }
            rs += __shfl_xor(rs, 1, 64);
            rs += __shfl_xor(rs, 2, 64);
            rs += __shfl_xor(rs, 4, 64);
            rs += __shfl_xor(rs, 8, 64);
            lrow[rr] += rs;
        }

#pragma unroll
        for (int hf = 0; hf < 2; ++hf) {
#pragma unroll
            for (int j = 0; j < 4; ++j)
#pragma unroll
                for (int rr = 0; rr < 4; ++rr) {
                    const int row = rbase + rr;
                    *(bf16*)(Pw + row * 128 + ((j * 32 + laneR * 2) ^ ((row & 7) << 4))) =
                        (bf16)sc[hf * 4 + j][rr];
                }
            __builtin_amdgcn_s_setprio(1);
#pragma unroll
            for (int kc = 0; kc < 2; ++kc) {
                bf16x8 pf = *(const bf16x8*)(Pw + laneR * 128 +
                                             ((kc * 64 + laneS * 16) ^ ((laneR & 7) << 4)));
                const int kcg = hf * 2 + kc;
                bf16x8 vf[8];
#pragma unroll
                for (int j = 0; j < 8; ++j) {
                    const int row = j * 16 + laneR;
                    vf[j] = *(const bf16x8*)((const char*)Vlds[buf] + row * 256 +
                                             ((kcg * 64 + laneS * 16) ^ ((row & 7) << 4)));
                }
#pragma unroll
                for (int j = 0; j < 8; ++j)
                    o[j] = __builtin_amdgcn_mfma_f32_16x16x32_bf16(pf, vf[j], o[j], 0, 0, 0);
            }
            __builtin_amdgcn_s_setprio(0);
        }

        if (tloc == qbcur) {
            float rinv[4];
#pragma unroll
            for (int rr = 0; rr < 4; ++rr) rinv[rr] = 1.0f / lrow[rr];
#pragma unroll
            for (int j = 0; j < 8; ++j)
#pragma unroll
                for (int rr = 0; rr < 4; ++rr) {
                    const size_t row = (size_t)q0w + rbase + rr;
                    Aout[row * 4096 + h * 128 + j * 16 + laneR] = (bf16)(o[j][rr] * rinv[rr]);
                }
            if (g < 16) {
                qbcur = qbB;
                q0w = qbB * 128 + wave * 16;
                tloc = 0;
                loadQ();
#pragma unroll
                for (int rr = 0; rr < 4; ++rr) { mrow[rr] = -1e30f; lrow[rr] = 0.f; }
#pragma unroll
                for (int j = 0; j < 8; ++j) o[j] = f32x4{0.f, 0.f, 0.f, 0.f};
            }
        } else {
            ++tloc;
        }

        __syncthreads();
    }
}

// ---------------- launch ----------------
extern "C" void kernel_launch(void* const* d_in, const int* in_sizes, int n_in,
                              void* d_out, int out_size, void* d_ws, size_t ws_size,
                              hipStream_t stream) {
    const float* hidden = (const float*)d_in[0];
    const float* Wq = (const float*)d_in[1];
    const float* Wk = (const float*)d_in[2];
    const float* Wv = (const float*)d_in[3];
    const float* Wo = (const float*)d_in[4];
    float* out = (float*)d_out;
    char* ws = (char*)d_ws;

    // workspace layout (bytes):
    bf16* hs = (bf16*)(ws + 0);                 // [2048][4096]        16 MiB (dead after QKV)
    bf16* Wb = (bf16*)(ws + 16777216);          // [10240][4096]       80 MiB (Wq|Wk|Wv|Wo)
    bf16* Cq = (bf16*)(ws + 100663296);         // [2048][6144]        24 MiB
    bf16* Qr = (bf16*)(ws + 125829120);         // [32][2048][128]     16 MiB
    bf16* Kr = (bf16*)(ws + 142606336);         // [8][2048][128]       4 MiB
    bf16* Vt = (bf16*)(ws + 146800640);         // [8][128][2048]       4 MiB
    bf16* At = (bf16*)(ws + 150994944);         // [2048][4096]        16 MiB
    float* ct = (float*)(ws + 0);               // rope cos table (aliases dead hs)
    float* st = (float*)(ws + 524288);          // rope sin table
    (void)ws_size; (void)in_sizes; (void)n_in; (void)out_size;

    // 1. fused casts (grid-stride, 2048 blocks)
    cvt_all_kernel<<<2048, 256, 0, stream>>>((const float4*)hidden, (const float4*)Wq,
                                             (const float4*)Wk, (const float4*)Wv,
                                             (const float4*)Wo, (ushort4*)hs, (ushort4*)Wb);

    // 2. fused QKV projection: ring + swizzle, 128x384 tiles -> 256 blocks
    gemm8p_kernel<384, false><<<dim3(16, 16), 512, 0, stream>>>(hs, Wb, Cq, 2048, 6144, 4096);

    // 3. rope tables, then fused RoPE + V-transpose (one launch)
    rope_table_kernel<<<512, 256, 0, stream>>>(ct, st);
    rope_tv_kernel<<<20736, 256, 0, stream>>>(Cq, Qr, Kr, Vt, ct, st);

    // 4. causal GQA flash attention (equal-work persistent, 256 blocks x 8 waves)
    flash_attn_kernel<<<256, 512, 0, stream>>>(Qr, Kr, Vt, At);

    // 5. output projection (ring + swizzle, 128x256 -> 256 blocks)
    gemm8p_kernel<256, true><<<dim3(16, 16), 512, 0, stream>>>(At, Wb + 25165824, out, 2048, 4096, 4096);
}

// Round 15
// 307.996 us; speedup vs baseline: 1.2300x; 1.0361x over previous
//
#include <hip/hip_runtime.h>

#define AS1 __attribute__((address_space(1)))
#define AS3 __attribute__((address_space(3)))

typedef __bf16 bf16;
typedef __bf16 bf16x8 __attribute__((ext_vector_type(8)));
typedef float f32x4 __attribute__((ext_vector_type(4)));

__device__ __forceinline__ void gld_lds16(const bf16* g, bf16* l) {
    __builtin_amdgcn_global_load_lds((const AS1 void*)g, (AS3 void*)l, 16, 0, 0);
}

#define SB0 __builtin_amdgcn_sched_barrier(0)

// ---------------- fused fp32 -> bf16 cast (all 5 tensors) + rope table gen ----------------
__global__ void cvt_all_kernel(const float4* __restrict__ h, const float4* __restrict__ wq,
                               const float4* __restrict__ wk, const float4* __restrict__ wv,
                               const float4* __restrict__ wo, ushort4* __restrict__ hs,
                               ushort4* __restrict__ wb, float* __restrict__ ct,
                               float* __restrict__ st) {
    for (int i = blockIdx.x * 256 + threadIdx.x; i < 12582912; i += 2048 * 256) {
        const float4* src;
        ushort4* dst;
        if (i < 2097152)      { src = h  + i;             dst = hs + i; }
        else if (i < 6291456) { src = wq + (i - 2097152); dst = wb + (i - 2097152); }
        else if (i < 7340032) { src = wk + (i - 6291456); dst = wb + 4194304 + (i - 6291456); }
        else if (i < 8388608) { src = wv + (i - 7340032); dst = wb + 5242880 + (i - 7340032); }
        else                  { src = wo + (i - 8388608); dst = wb + 6291456 + (i - 8388608); }
        const float4 v = *src;
        ushort4 r;
        r.x = __builtin_bit_cast(unsigned short, (bf16)v.x);
        r.y = __builtin_bit_cast(unsigned short, (bf16)v.y);
        r.z = __builtin_bit_cast(unsigned short, (bf16)v.z);
        r.w = __builtin_bit_cast(unsigned short, (bf16)v.w);
        *dst = r;
    }
    if (blockIdx.x < 512) {                    // rope tables [2048][64]
        const int idx = blockIdx.x * 256 + threadIdx.x;
        const int f = idx & 63;
        const int s = idx >> 6;
        const float th = s * expf(-0.14391156831212787f * (float)f);
        ct[idx] = cosf(th);
        st[idx] = sinf(th);
    }
}

// ---------------- QKV GEMM (ring + swizzle, BN=384) with FUSED rope + V-transpose epilogue ----------------
// Core K-loop identical to the proven gemm8p<384>. After the final vmcnt(0)+barrier the
// ring LDS is dead; the 128x384 block output is staged there (stride 386 = odd dword ->
// conflict-free column reads), then: q cols (c<4096) and k cols (4096<=c<5120) get RoPE
// (pairs f,f+64 are tile-local since BN=384 is 128-aligned) written to Qr/Kr [h][s][d];
// v cols (c>=5120) are transposed to Vt [hkv][d][s]. q scaled by log2e/sqrt(D).
__launch_bounds__(512, 2)
__global__ void gemm_qkv_kernel(const bf16* __restrict__ A, const bf16* __restrict__ W,
                                bf16* __restrict__ Qr, bf16* __restrict__ Kr,
                                bf16* __restrict__ Vt, const float* __restrict__ ct,
                                const float* __restrict__ st, int K) {
    __shared__ __align__(16) char smem[131072];
    bf16* AslB = (bf16*)smem;                  // 4 slots x 128x32 (32KB)
    bf16* BslB = (bf16*)(smem + 32768);        // 4 slots x 384x32 (96KB)
    bf16* LDSe = (bf16*)smem;                  // epilogue overlay: [128][386] (98.8KB)

    const int tn = blockIdx.x * 384;
    const int tm = blockIdx.y * 128;
    const int tid = threadIdx.x;
    const int wave = tid >> 6;
    const int lane = tid & 63;
    const int laneR = lane & 15;
    const int laneS = lane >> 4;
    const int wmB = (wave >> 2) * 64;
    const int wnB = (wave & 3) * 96;
    const int NT = K >> 5;
    const int sofs = (laneS ^ ((laneR >> 1) & 3)) << 3;

    auto stage = [&](int t) {
        const int slot = t & 3;
        const int k0 = t << 5;
        {
            const int row = tid >> 2, g = tid & 3;
            const int sg = g ^ ((row >> 1) & 3);
            gld_lds16(A + (size_t)(tm + row) * K + k0 + sg * 8, AslB + slot * 4096 + wave * 512);
        }
#pragma unroll
        for (int i = 0; i < 3; ++i) {
            const int row = i * 128 + (tid >> 2), g = tid & 3;
            const int sg = g ^ ((row >> 1) & 3);
            gld_lds16(W + (size_t)(tn + row) * K + k0 + sg * 8,
                      BslB + slot * 12288 + i * 4096 + wave * 512);
        }
    };

    f32x4 acc[4][6] = {};

    stage(0); stage(1); stage(2);
    asm volatile("s_waitcnt vmcnt(8)" ::: "memory");
    SB0;
    __builtin_amdgcn_s_barrier();
    SB0;

    for (int t = 0; t < NT; ++t) {
        const int slot = t & 3;
        bf16x8 af[4], bfr[6];
#pragma unroll
        for (int mf = 0; mf < 4; ++mf)
            af[mf] = *(const bf16x8*)(AslB + slot * 4096 + (wmB + mf * 16 + laneR) * 32 + sofs);
#pragma unroll
        for (int nf = 0; nf < 6; ++nf)
            bfr[nf] = *(const bf16x8*)(BslB + slot * 12288 + (wnB + nf * 16 + laneR) * 32 + sofs);

        if (t + 3 < NT) stage(t + 3);

#pragma unroll
        for (int mf = 0; mf < 4; ++mf)
#pragma unroll
            for (int nf = 0; nf < 6; ++nf)
                acc[mf][nf] = __builtin_amdgcn_mfma_f32_16x16x32_bf16(af[mf], bfr[nf], acc[mf][nf], 0, 0, 0);

        SB0;
        if (t + 3 < NT)       asm volatile("s_waitcnt vmcnt(8)" ::: "memory");
        else if (t + 3 == NT) asm volatile("s_waitcnt vmcnt(4)" ::: "memory");
        else                  asm volatile("s_waitcnt vmcnt(0)" ::: "memory");
        SB0;
        __builtin_amdgcn_s_barrier();
        SB0;
    }

    // ---- fused epilogue ----
    // Phase A: accumulators -> LDSe[row][col], stride 386
    const int rbase = laneS * 4;
#pragma unroll
    for (int mf = 0; mf < 4; ++mf)
#pragma unroll
        for (int nf = 0; nf < 6; ++nf)
#pragma unroll
            for (int rr = 0; rr < 4; ++rr) {
                const int row = wmB + mf * 16 + rbase + rr;
                const int col = wnB + nf * 16 + laneR;
                LDSe[row * 386 + col] = (bf16)acc[mf][nf][rr];
            }
    __syncthreads();

    // Phase B1: rope on q/k pairs (f-major mapping -> coalesced Qr/Kr writes)
    const float QSC = 0.12751743561884394f;    // (1/sqrt(128)) * log2(e)
    const int nqk = min(max(5120 - tn, 0), 384);   // q/k cols in tile (multiple of 128)
    const int nqkb = nqk >> 7;
    for (int it = 0; it < nqkb * 16; ++it) {
        const int g = it * 512 + tid;          // blk*8192 + row*64 + f
        const int f = g & 63;
        const int row = (g >> 6) & 127;
        const int blk = g >> 13;
        const int c = tn + blk * 128;          // head base col
        const float x1 = (float)LDSe[row * 386 + blk * 128 + f];
        const float x2 = (float)LDSe[row * 386 + blk * 128 + f + 64];
        const int s = tm + row;
        const float cs = ct[(s << 6) + f], sn = st[(s << 6) + f];
        const float o1 = x1 * cs - x2 * sn;
        const float o2 = x2 * cs + x1 * sn;
        if (c < 4096) {
            bf16* dst = Qr + ((size_t)(c >> 7) * 2048 + s) * 128 + f;
            dst[0]  = (bf16)(o1 * QSC);
            dst[64] = (bf16)(o2 * QSC);
        } else {
            bf16* dst = Kr + ((size_t)((c - 4096) >> 7) * 2048 + s) * 128 + f;
            dst[0]  = (bf16)o1;
            dst[64] = (bf16)o2;
        }
    }

    // Phase B2: V transpose (s-major mapping -> coalesced Vt writes; LDS column reads
    // conflict-free via odd-dword stride 386)
    const int nv = 384 - nqk;
    for (int it = 0; it < (nv >> 2); ++it) {
        const int g = it * 512 + tid;
        const int row = g & 127;
        const int cv = g >> 7;                 // 0..nv-1
        const int dv = tn + nqk + cv - 5120;   // hkv*128 + d
        Vt[((size_t)(dv >> 7) * 128 + (dv & 127)) * 2048 + tm + row] =
            LDSe[row * 386 + nqk + cv];
    }
}

// ---------------- GEMM: counted-vmcnt 4-slot ring + slot-XOR swizzle (O-proj, frozen) ----------------
template <int BN, bool OUTF32>
__launch_bounds__(512, 2)
__global__ void gemm8p_kernel(const bf16* __restrict__ A, const bf16* __restrict__ W,
                              void* __restrict__ Cout, int M, int N, int K) {
    constexpr int NF = BN / 64;
    constexpr int IB = BN / 128;
    __shared__ __align__(16) bf16 Asl[4][128 * 32];
    __shared__ __align__(16) bf16 Bsl[4][BN * 32];

    const int tn = blockIdx.x * BN;
    const int tm = blockIdx.y * 128;
    const int tid = threadIdx.x;
    const int wave = tid >> 6;
    const int lane = tid & 63;
    const int laneR = lane & 15;
    const int laneS = lane >> 4;
    const int wmB = (wave >> 2) * 64;
    const int wnB = (wave & 3) * (BN / 4);
    const int NT = K >> 5;
    const int sofs = (laneS ^ ((laneR >> 1) & 3)) << 3;

    auto stage = [&](int t) {
        const int slot = t & 3;
        const int k0 = t << 5;
        {
            const int row = tid >> 2, g = tid & 3;
            const int sg = g ^ ((row >> 1) & 3);
            gld_lds16(A + (size_t)(tm + row) * K + k0 + sg * 8, &Asl[slot][wave * 512]);
        }
#pragma unroll
        for (int i = 0; i < IB; ++i) {
            const int row = i * 128 + (tid >> 2), g = tid & 3;
            const int sg = g ^ ((row >> 1) & 3);
            gld_lds16(W + (size_t)(tn + row) * K + k0 + sg * 8,
                      &Bsl[slot][i * 4096 + wave * 512]);
        }
    };

    f32x4 acc[4][NF] = {};

    stage(0); stage(1); stage(2);
    if constexpr (BN == 384) asm volatile("s_waitcnt vmcnt(8)" ::: "memory");
    else                     asm volatile("s_waitcnt vmcnt(6)" ::: "memory");
    SB0;
    __builtin_amdgcn_s_barrier();
    SB0;

    for (int t = 0; t < NT; ++t) {
        const int slot = t & 3;
        bf16x8 af[4], bfr[NF];
#pragma unroll
        for (int mf = 0; mf < 4; ++mf)
            af[mf] = *(const bf16x8*)&Asl[slot][(wmB + mf * 16 + laneR) * 32 + sofs];
#pragma unroll
        for (int nf = 0; nf < NF; ++nf)
            bfr[nf] = *(const bf16x8*)&Bsl[slot][(wnB + nf * 16 + laneR) * 32 + sofs];

        if (t + 3 < NT) stage(t + 3);

#pragma unroll
        for (int mf = 0; mf < 4; ++mf)
#pragma unroll
            for (int nf = 0; nf < NF; ++nf)
                acc[mf][nf] = __builtin_amdgcn_mfma_f32_16x16x32_bf16(af[mf], bfr[nf], acc[mf][nf], 0, 0, 0);

        SB0;
        if (t + 3 < NT) {
            if constexpr (BN == 384) asm volatile("s_waitcnt vmcnt(8)" ::: "memory");
            else                     asm volatile("s_waitcnt vmcnt(6)" ::: "memory");
        } else if (t + 3 == NT) {
            if constexpr (BN == 384) asm volatile("s_waitcnt vmcnt(4)" ::: "memory");
            else                     asm volatile("s_waitcnt vmcnt(3)" ::: "memory");
        } else {
            asm volatile("s_waitcnt vmcnt(0)" ::: "memory");
        }
        SB0;
        __builtin_amdgcn_s_barrier();
        SB0;
    }

    const int rbase = laneS * 4;
#pragma unroll
    for (int mf = 0; mf < 4; ++mf)
#pragma unroll
        for (int nf = 0; nf < NF; ++nf)
#pragma unroll
            for (int rr = 0; rr < 4; ++rr) {
                const size_t row = (size_t)tm + wmB + mf * 16 + rbase + rr;
                const size_t col = (size_t)tn + wnB + nf * 16 + laneR;
                if constexpr (OUTF32) ((float*)Cout)[row * N + col] = acc[mf][nf][rr];
                else                  ((bf16*)Cout)[row * N + col] = (bf16)acc[mf][nf][rr];
            }
    (void)M;
}

// ---------------- causal GQA flash attention: equal-work persistent, 8 waves (frozen) ----------------
__launch_bounds__(512, 1)
__global__ void flash_attn_kernel(const bf16* __restrict__ Qr, const bf16* __restrict__ Kr,
                                  const bf16* __restrict__ Vt, bf16* __restrict__ Aout) {
    __shared__ __align__(16) bf16 Klds[2][128 * 128];
    __shared__ __align__(16) bf16 Vlds[2][128 * 128];
    __shared__ __align__(16) char Plds[8][2048];

    const int bid = blockIdx.x;
    const int hkv = bid & 7;
    const int r = bid >> 3;
    const int h = hkv * 4 + (r & 3);
    const int pa = r >> 2;
    const int qbA = 15 - pa, qbB = pa;
    const int tid = threadIdx.x;
    const int wave = tid >> 6, lane = tid & 63;
    const int laneR = lane & 15;
    const int laneS = lane >> 4;
    const int laneK = laneS * 8;
    const int rbase = laneS * 4;

    const bf16* Kh = Kr + (size_t)hkv * 2048 * 128;
    const bf16* Vh = Vt + (size_t)hkv * 128 * 2048;
    char* Pw = Plds[wave];

    auto stageK = [&](int kv0, int buf) {
#pragma unroll
        for (int s = 0; s < 4; ++s) {
            const int chunk = wave * 4 + s;
            const int L = chunk * 64 + lane;
            const int row = L >> 4, sl = L & 15;
            gld_lds16(Kh + (size_t)(kv0 + row) * 128 + ((sl ^ (row & 7)) << 3),
                      &Klds[buf][chunk * 512]);
        }
    };
    auto stageV = [&](int kv0, int buf) {
#pragma unroll
        for (int s = 0; s < 4; ++s) {
            const int chunk = wave * 4 + s;
            const int L = chunk * 64 + lane;
            const int row = L >> 4, sl = L & 15;
            gld_lds16(Vh + (size_t)row * 2048 + kv0 + ((sl ^ (row & 7)) << 3),
                      &Vlds[buf][chunk * 512]);
        }
    };

    int qbcur = qbA;
    int q0w = qbA * 128 + wave * 16;
    int tloc = 0;

    bf16x8 qf[4];
    auto loadQ = [&]() {
#pragma unroll
        for (int kc = 0; kc < 4; ++kc)
            qf[kc] = *(const bf16x8*)&Qr[((size_t)h * 2048 + q0w + laneR) * 128 + kc * 32 + laneK];
    };
    loadQ();

    f32x4 o[8] = {};
    float mrow[4], lrow[4];
#pragma unroll
    for (int rr = 0; rr < 4; ++rr) { mrow[rr] = -1e30f; lrow[rr] = 0.f; }

    stageK(0, 0);
    stageV(0, 0);
    __syncthreads();

    for (int g = 0; g < 17; ++g) {
        const int buf = g & 1;
        if (g < 16) {
            const int tn = (g + 1 <= qbA) ? (g + 1) : (g - qbA);
            stageK(tn * 128, buf ^ 1);
            stageV(tn * 128, buf ^ 1);
        }
        const int kv0 = tloc * 128;

        f32x4 sc[8] = {};
        __builtin_amdgcn_s_setprio(1);
#pragma unroll
        for (int kc = 0; kc < 4; ++kc) {
            bf16x8 kf[8];
#pragma unroll
            for (int j = 0; j < 8; ++j) {
                const int row = j * 16 + laneR;
                kf[j] = *(const bf16x8*)((const char*)Klds[buf] + row * 256 +
                                         ((kc * 64 + laneS * 16) ^ ((row & 7) << 4)));
            }
#pragma unroll
            for (int j = 0; j < 8; ++j)
                sc[j] = __builtin_amdgcn_mfma_f32_16x16x32_bf16(qf[kc], kf[j], sc[j], 0, 0, 0);
        }
        __builtin_amdgcn_s_setprio(0);

        if (tloc == qbcur) {
#pragma unroll
            for (int j = 0; j < 8; ++j)
#pragma unroll
                for (int rr = 0; rr < 4; ++rr) {
                    const int qr = q0w + rbase + rr;
                    const int kr = kv0 + j * 16 + laneR;
                    if (kr > qr) sc[j][rr] = -1e30f;
                }
        }

#pragma unroll
        for (int rr = 0; rr < 4; ++rr) {
            float v = sc[0][rr];
#pragma unroll
            for (int j = 1; j < 8; ++j) v = fmaxf(v, sc[j][rr]);
            v = fmaxf(v, __shfl_xor(v, 1, 64));
            v = fmaxf(v, __shfl_xor(v, 2, 64));
            v = fmaxf(v, __shfl_xor(v, 4, 64));
            v = fmaxf(v, __shfl_xor(v, 8, 64));
            float m0 = mrow[rr];
            if (v - m0 > 8.0f) {
                const float fac = __builtin_exp2f(m0 - v);
                mrow[rr] = v;
                m0 = v;
                lrow[rr] *= fac;
#pragma unroll
                for (int j = 0; j < 8; ++j) o[j][rr] *= fac;
            }
            float rs = 0.f;
#pragma unroll
            for (int j = 0; j < 8; ++j) {
                const float p = __builtin_exp2f(sc[j][rr] - m0);
                sc[j][rr] = p;
                rs += p;
            }
            rs += __shfl_xor(rs, 1, 64);
            rs += __shfl_xor(rs, 2, 64);
            rs += __shfl_xor(rs, 4, 64);
            rs += __shfl_xor(rs, 8, 64);
            lrow[rr] += rs;
        }

#pragma unroll
        for (int hf = 0; hf < 2; ++hf) {
#pragma unroll
            for (int j = 0; j < 4; ++j)
#pragma unroll
                for (int rr = 0; rr < 4; ++rr) {
                    const int row = rbase + rr;
                    *(bf16*)(Pw + row * 128 + ((j * 32 + laneR * 2) ^ ((row & 7) << 4))) =
                        (bf16)sc[hf * 4 + j][rr];
                }
            __builtin_amdgcn_s_setprio(1);
#pragma unroll
            for (int kc = 0; kc < 2; ++kc) {
                bf16x8 pf = *(const bf16x8*)(Pw + laneR * 128 +
                                             ((kc * 64 + laneS * 16) ^ ((laneR & 7) << 4)));
                const int kcg = hf * 2 + kc;
                bf16x8 vf[8];
#pragma unroll
                for (int j = 0; j < 8; ++j) {
                    const int row = j * 16 + laneR;
                    vf[j] = *(const bf16x8*)((const char*)Vlds[buf] + row * 256 +
                                             ((kcg * 64 + laneS * 16) ^ ((row & 7) << 4)));
                }
#pragma unroll
                for (int j = 0; j < 8; ++j)
                    o[j] = __builtin_amdgcn_mfma_f32_16x16x32_bf16(pf, vf[j], o[j], 0, 0, 0);
            }
            __builtin_amdgcn_s_setprio(0);
        }

        if (tloc == qbcur) {
            float rinv[4];
#pragma unroll
            for (int rr = 0; rr < 4; ++rr) rinv[rr] = 1.0f / lrow[rr];
#pragma unroll
            for (int j = 0; j < 8; ++j)
#pragma unroll
                for (int rr = 0; rr < 4; ++rr) {
                    const size_t row = (size_t)q0w + rbase + rr;
                    Aout[row * 4096 + h * 128 + j * 16 + laneR] = (bf16)(o[j][rr] * rinv[rr]);
                }
            if (g < 16) {
                qbcur = qbB;
                q0w = qbB * 128 + wave * 16;
                tloc = 0;
                loadQ();
#pragma unroll
                for (int rr = 0; rr < 4; ++rr) { mrow[rr] = -1e30f; lrow[rr] = 0.f; }
#pragma unroll
                for (int j = 0; j < 8; ++j) o[j] = f32x4{0.f, 0.f, 0.f, 0.f};
            }
        } else {
            ++tloc;
        }

        __syncthreads();
    }
}

// ---------------- launch ----------------
extern "C" void kernel_launch(void* const* d_in, const int* in_sizes, int n_in,
                              void* d_out, int out_size, void* d_ws, size_t ws_size,
                              hipStream_t stream) {
    const float* hidden = (const float*)d_in[0];
    const float* Wq = (const float*)d_in[1];
    const float* Wk = (const float*)d_in[2];
    const float* Wv = (const float*)d_in[3];
    const float* Wo = (const float*)d_in[4];
    float* out = (float*)d_out;
    char* ws = (char*)d_ws;

    // workspace layout (bytes):
    bf16* hs = (bf16*)(ws + 0);                 // [2048][4096]        16 MiB (live through QKV)
    bf16* Wb = (bf16*)(ws + 16777216);          // [10240][4096]       80 MiB (Wq|Wk|Wv|Wo)
    float* ct = (float*)(ws + 100663296);       // rope cos table [2048][64] (old Cq region)
    float* st = (float*)(ws + 101187584);       // rope sin table
    bf16* Qr = (bf16*)(ws + 125829120);         // [32][2048][128]     16 MiB
    bf16* Kr = (bf16*)(ws + 142606336);         // [8][2048][128]       4 MiB
    bf16* Vt = (bf16*)(ws + 146800640);         // [8][128][2048]       4 MiB
    bf16* At = (bf16*)(ws + 150994944);         // [2048][4096]        16 MiB
    (void)ws_size; (void)in_sizes; (void)n_in; (void)out_size;

    // 1. fused casts + rope tables
    cvt_all_kernel<<<2048, 256, 0, stream>>>((const float4*)hidden, (const float4*)Wq,
                                             (const float4*)Wk, (const float4*)Wv,
                                             (const float4*)Wo, (ushort4*)hs, (ushort4*)Wb,
                                             ct, st);

    // 2. fused QKV projection + RoPE + V-transpose (128x384 tiles -> 256 blocks)
    gemm_qkv_kernel<<<dim3(16, 16), 512, 0, stream>>>(hs, Wb, Qr, Kr, Vt, ct, st, 4096);

    // 3. causal GQA flash attention (equal-work persistent, 256 blocks x 8 waves)
    flash_attn_kernel<<<256, 512, 0, stream>>>(Qr, Kr, Vt, At);

    // 4. output projection (ring + swizzle, 128x256 -> 256 blocks)
    gemm8p_kernel<256, true><<<dim3(16, 16), 512, 0, stream>>>(At, Wb + 25165824, out, 2048, 4096, 4096);
}